// Round 15
// baseline (573.737 us; speedup 1.0000x reference)
//
#include <hip/hip_runtime.h>
#include <stdint.h>

#define DM 1024
#define NH 16
#define DK 64
#define NB 4
#define SS 2048

// Q pre-scale: (1/sqrt(64)) * log2(e) so scores are in log2 domain.
#define QSCALE 0.18033688011112042f

typedef float f32x4 __attribute__((ext_vector_type(4)));
typedef short s16x8 __attribute__((ext_vector_type(8)));

typedef __attribute__((address_space(1))) unsigned int glb_u32;
typedef __attribute__((address_space(3))) unsigned int lds_u32;

static __device__ __forceinline__ void gload16(const void* g, void* lds) {
  __builtin_amdgcn_global_load_lds((glb_u32*)g, (lds_u32*)lds, 16, 0, 0);
}

static __device__ __forceinline__ unsigned short f2bf(float f) {
  union { float f; unsigned int u; } v;
  v.f = f;
  unsigned int u = v.u + 0x7fffu + ((v.u >> 16) & 1u);  // RNE
  return (unsigned short)(u >> 16);
}

static __device__ __forceinline__ unsigned int cvtpk(float lo, float hi) {
  unsigned int r;
  asm("v_cvt_pk_bf16_f32 %0, %1, %2" : "=v"(r) : "v"(lo), "v"(hi));
  return r;
}

// Bare hardware 2^x / log2(x) via compiler-known builtins.
static __device__ __forceinline__ float vexp2(float x) {
  return __builtin_amdgcn_exp2f(x);
}
static __device__ __forceinline__ float vlog2(float x) {
  return __builtin_amdgcn_logf(x);
}

static __device__ __forceinline__ f32x4 mfma16(s16x8 a, s16x8 b, f32x4 c) {
  return __builtin_amdgcn_mfma_f32_16x16x32_bf16(a, b, c, 0, 0, 0);
}

// ---------------- convert x (fp32 -> bf16), 4 elems/thread ----------------
__global__ __launch_bounds__(256) void k_cvt_x(const float* __restrict__ x,
                                               unsigned short* __restrict__ xh) {
  int i = blockIdx.x * 256 + threadIdx.x;
  float4 v = ((const float4*)x)[i];
  ushort4 h;
  h.x = f2bf(v.x); h.y = f2bf(v.y); h.z = f2bf(v.z); h.w = f2bf(v.w);
  ((ushort4*)xh)[i] = h;
}

// ------- transpose-convert 4 weights in one launch (z selects W) -------
__global__ void k_cvt_w4(const float* __restrict__ Wq, const float* __restrict__ Wk,
                         const float* __restrict__ Wv, const float* __restrict__ Wo,
                         unsigned short* __restrict__ WTqkv,
                         unsigned short* __restrict__ WTo) {
  __shared__ float t[32][33];
  int z = blockIdx.z;
  const float* W = z == 0 ? Wq : (z == 1 ? Wk : (z == 2 ? Wv : Wo));
  unsigned short* dst = z < 3 ? WTqkv + (size_t)z * 1024 * 1024 : WTo;
  int tx = threadIdx.x, ty = threadIdx.y;          // 32 x 8
  int bx = blockIdx.x * 32, by = blockIdx.y * 32;  // bx: out cols, by: in rows
  #pragma unroll
  for (int i = 0; i < 4; i++)
    t[ty + 8 * i][tx] = W[(size_t)(by + ty + 8 * i) * DM + bx + tx];
  __syncthreads();
  #pragma unroll
  for (int i = 0; i < 4; i++)
    dst[(size_t)(bx + ty + 8 * i) * DM + by + tx] = f2bf(t[tx][ty + 8 * i]);
}

// ---------------- 128x128 GEMM core (shared by both proj kernels) ----------------
static __device__ __forceinline__ void gemm_core(const unsigned short* __restrict__ A,
                                                 const unsigned short* __restrict__ BT,
                                                 unsigned short* lA, unsigned short* lB,
                                                 f32x4 acc[4][4], int bm, int bn) {
  const int tid = threadIdx.x;
  const int lane = tid & 63, wv = tid >> 6;
  const int wy = wv >> 1, wx = wv & 1;
  const int l15 = lane & 15, l4 = lane >> 4;

  for (int k0 = 0; k0 < DM; k0 += 32) {
    #pragma unroll
    for (int r = 0; r < 2; r++) {
      int chunk = r * 256 + tid;
      int row = chunk >> 2, c4 = chunk & 3;  // [128 rows][32 cols], 16B chunks
      gload16(A + (size_t)(bm + row) * DM + k0 + c4 * 8,
              (char*)lA + (r * 256 + wv * 64) * 16);
      gload16(BT + (size_t)(bn + row) * DM + k0 + c4 * 8,
              (char*)lB + (r * 256 + wv * 64) * 16);
    }
    __syncthreads();
    s16x8 af[4], bf[4];
    #pragma unroll
    for (int i = 0; i < 4; i++)
      af[i] = *(const s16x8*)&lA[(wy * 64 + i * 16 + l15) * 32 + l4 * 8];
    #pragma unroll
    for (int j = 0; j < 4; j++)
      bf[j] = *(const s16x8*)&lB[(wx * 64 + j * 16 + l15) * 32 + l4 * 8];
    #pragma unroll
    for (int i = 0; i < 4; i++)
      #pragma unroll
      for (int j = 0; j < 4; j++)
        acc[i][j] = mfma16(af[i], bf[j], acc[i][j]);
    __syncthreads();
  }
}

// Fused QKV projection: BT = stacked [3072 out][1024 in]; grid (24, 64).
__global__ __launch_bounds__(256) void k_proj_qkv(
    const unsigned short* __restrict__ A, const unsigned short* __restrict__ BT,
    const float* __restrict__ bq, const float* __restrict__ bk,
    const float* __restrict__ bv, unsigned short* __restrict__ Qh,
    unsigned short* __restrict__ Kh, unsigned short* __restrict__ VhT) {
  __shared__ unsigned short lA[128 * 32];
  __shared__ unsigned short lB[128 * 32];
  const int tid = threadIdx.x;
  const int lane = tid & 63, wv = tid >> 6;
  const int wy = wv >> 1, wx = wv & 1;
  const int l15 = lane & 15, l4 = lane >> 4;
  const int bm = blockIdx.y * 128, bn = blockIdx.x * 128;

  const f32x4 fz = {0.f, 0.f, 0.f, 0.f};
  f32x4 acc[4][4];
  #pragma unroll
  for (int i = 0; i < 4; i++)
    #pragma unroll
    for (int j = 0; j < 4; j++) acc[i][j] = fz;

  gemm_core(A, BT, lA, lB, acc, bm, bn);

  // C/D: col = lane&15, row = (lane>>4)*4 + reg
  #pragma unroll
  for (int j = 0; j < 4; j++) {
    int c = bn + wx * 64 + j * 16 + l15;
    float bvv = c < 1024 ? bq[c] : (c < 2048 ? bk[c - 1024] : bv[c - 2048]);
    int cc = c & 1023, h = cc >> 6, d = cc & 63, proj = c >> 10;
    #pragma unroll
    for (int i = 0; i < 4; i++) {
      int rbase = bm + wy * 64 + i * 16 + l4 * 4;
      #pragma unroll
      for (int r = 0; r < 4; r++) {
        float v = acc[i][j][r] + bvv;
        int row = rbase + r;
        int b = row >> 11, s = row & 2047;
        size_t qk = (((size_t)(b * NH + h)) * SS + s) * DK + d;
        if (proj == 0)
          Qh[qk] = f2bf(v * QSCALE);
        else if (proj == 1)
          Kh[qk] = f2bf(v);
        else
          VhT[(((size_t)(b * NH + h)) * DK + d) * SS + s] = f2bf(v);
      }
    }
  }
}

// Output projection: fp32 out, nt stores.
__global__ __launch_bounds__(256) void k_proj_o(const unsigned short* __restrict__ A,
                                                const unsigned short* __restrict__ BT,
                                                const float* __restrict__ bias,
                                                float* __restrict__ outp) {
  __shared__ unsigned short lA[128 * 32];
  __shared__ unsigned short lB[128 * 32];
  const int tid = threadIdx.x;
  const int lane = tid & 63, wv = tid >> 6;
  const int wy = wv >> 1, wx = wv & 1;
  const int l15 = lane & 15, l4 = lane >> 4;
  const int bm = blockIdx.y * 128, bn = blockIdx.x * 128;

  const f32x4 fz = {0.f, 0.f, 0.f, 0.f};
  f32x4 acc[4][4];
  #pragma unroll
  for (int i = 0; i < 4; i++)
    #pragma unroll
    for (int j = 0; j < 4; j++) acc[i][j] = fz;

  gemm_core(A, BT, lA, lB, acc, bm, bn);

  #pragma unroll
  for (int j = 0; j < 4; j++) {
    int c = bn + wx * 64 + j * 16 + l15;
    float bvv = bias[c];
    #pragma unroll
    for (int i = 0; i < 4; i++) {
      int rbase = bm + wy * 64 + i * 16 + l4 * 4;
      #pragma unroll
      for (int r = 0; r < 4; r++) {
        float v = acc[i][j][r] + bvv;
        __builtin_nontemporal_store(v, outp + (size_t)(rbase + r) * DM + c);
      }
    }
  }
}

// ---------------- fused attention, KVBLK=64, XCD-pinned heads ----------------
// Pass A: barrier-free, LDS-free — swapped-QK makes K fragments lane-local
// row reads; K is L2-resident (XCD pinning), waves free-run their 32 tiles.
// Pass B: unchanged from round-13/14 best (store-BW-floor schedule).
__global__ __launch_bounds__(256, 3) void k_attn(const unsigned short* __restrict__ Qh,
                                                 const unsigned short* __restrict__ Kh,
                                                 const unsigned short* __restrict__ VhT,
                                                 float* __restrict__ attnO,
                                                 unsigned short* __restrict__ AOh) {
  __shared__ unsigned short sm[24576];

  const int tid = threadIdx.x;
  const int lane = tid & 63, wv = tid >> 6;
  const int l15 = lane & 15, l4 = lane >> 4;
  const int bid = blockIdx.x;
  const int xcd = bid & 7, t = bid >> 3;
  const int bh = ((t >> 4) << 3) | xcd;
  const int q0 = (t & 15) * 128;
  const size_t kbase = (size_t)bh * SS * DK;
  const f32x4 fz = {0.f, 0.f, 0.f, 0.f};

  auto stageK = [&](int kt, unsigned short* dst) {
    #pragma unroll
    for (int r = 0; r < 2; r++) {
      int chunk = r * 256 + tid;
      int row = chunk >> 3, c = chunk & 7;
      int cs = c ^ (row & 7);
      gload16(Kh + kbase + (size_t)(kt * 64 + row) * DK + cs * 8,
              (char*)dst + (r * 256 + wv * 64) * 16);
    }
  };
  auto stageV = [&](int kt, unsigned short* dst) {
    #pragma unroll
    for (int r = 0; r < 2; r++) {
      int chunk = r * 256 + tid;
      int row = chunk >> 3, c = chunk & 7;
      int cs = c ^ (row & 7);
      gload16(VhT + kbase + (size_t)row * SS + kt * 64 + cs * 8,
              (char*)dst + (r * 256 + wv * 64) * 16);
    }
  };

  s16x8 qf[2][2];
  #pragma unroll
  for (int qt = 0; qt < 2; qt++)
    #pragma unroll
    for (int ks = 0; ks < 2; ks++) {
      int row = q0 + wv * 32 + qt * 16 + l15;
      qf[qt][ks] = *(const s16x8*)&Qh[kbase + (size_t)row * DK + ks * 32 + l4 * 8];
    }

  // ---- Pass A: direct global->reg K fragments, no LDS, no barriers ----
  float lsA[2] = {0.f, 0.f};
  {
    const unsigned short* kp = Kh + kbase;
    for (int kt = 0; kt < 32; kt++) {
      s16x8 kf[4][2];
      #pragma unroll
      for (int nt = 0; nt < 4; nt++) {
        int kr = kt * 64 + nt * 16 + l15;
        kf[nt][0] = *(const s16x8*)&kp[(size_t)kr * DK + l4 * 8];
        kf[nt][1] = *(const s16x8*)&kp[(size_t)kr * DK + 32 + l4 * 8];
      }
      #pragma unroll
      for (int nt = 0; nt < 4; nt++) {
        #pragma unroll
        for (int qt = 0; qt < 2; qt++) {
          f32x4 s = fz;
          s = mfma16(kf[nt][0], qf[qt][0], s);
          s = mfma16(kf[nt][1], qf[qt][1], s);
          lsA[qt] += vexp2(s[0]) + vexp2(s[1]) + vexp2(s[2]) + vexp2(s[3]);
        }
      }
    }
  }

  float l2l[2];
  #pragma unroll
  for (int qt = 0; qt < 2; qt++) {
    float v = lsA[qt];
    v += __shfl_xor(v, 16);
    v += __shfl_xor(v, 32);
    l2l[qt] = -vlog2(v);  // p = 2^(s + l2l)
  }

  // ---- Pass B (unchanged) ----
  f32x4 oacc[2][4];
  #pragma unroll
  for (int qt = 0; qt < 2; qt++)
    #pragma unroll
    for (int dt = 0; dt < 4; dt++) oacc[qt][dt] = fz;

  float* ap0 = attnO + ((size_t)bh * SS + q0 + wv * 32 + l15) * SS;
  float* ap1 = ap0 + (size_t)16 * SS;

  stageK(0, sm);
  stageV(0, sm + 12288);
  stageK(1, sm + 4096);
  stageV(1, sm + 12288 + 4096);
  asm volatile("s_waitcnt vmcnt(4)" ::: "memory");
  __builtin_amdgcn_s_barrier();

  for (int kt = 0; kt < 32; kt++) {
    int sl = kt % 3;
    const unsigned short* lk = sm + sl * 4096;
    const unsigned short* lv = sm + 12288 + sl * 4096;
    if (kt < 30) {
      int s2 = (kt + 2) % 3;
      stageK(kt + 2, sm + s2 * 4096);
      stageV(kt + 2, sm + 12288 + s2 * 4096);
    }
    __builtin_amdgcn_sched_barrier(0);

    unsigned int pw[2][4][2];
    #pragma unroll
    for (int nt = 0; nt < 4; nt++) {
      int krow = nt * 16 + l15;
      s16x8 kf0 = *(const s16x8*)&lk[krow * 64 + ((l4) ^ (krow & 7)) * 8];
      s16x8 kf1 = *(const s16x8*)&lk[krow * 64 + ((4 + l4) ^ (krow & 7)) * 8];
      #pragma unroll
      for (int qt = 0; qt < 2; qt++) {
        f32x4 s = fz;
        s = mfma16(kf0, qf[qt][0], s);
        s = mfma16(kf1, qf[qt][1], s);
        f32x4 p;
        p[0] = vexp2(s[0] + l2l[qt]);
        p[1] = vexp2(s[1] + l2l[qt]);
        p[2] = vexp2(s[2] + l2l[qt]);
        p[3] = vexp2(s[3] + l2l[qt]);
        float* ap = (qt == 0 ? ap0 : ap1) + kt * 64 + nt * 16 + l4 * 4;
        __builtin_nontemporal_store(p, (f32x4*)ap);
        pw[qt][nt][0] = cvtpk(p[0], p[1]);
        pw[qt][nt][1] = cvtpk(p[2], p[3]);
      }
    }

    #pragma unroll
    for (int ks = 0; ks < 2; ks++) {
      s16x8 vf[4];
      #pragma unroll
      for (int dt = 0; dt < 4; dt++) {
        int vrow = dt * 16 + l15;
        int c0 = (4 * ks + (l4 >> 1)) ^ (vrow & 7);
        int c1 = (4 * ks + 2 + (l4 >> 1)) ^ (vrow & 7);
        union { unsigned long long q[2]; s16x8 v; } vv;
        vv.q[0] = *(const unsigned long long*)&lv[vrow * 64 + c0 * 8 + (l4 & 1) * 4];
        vv.q[1] = *(const unsigned long long*)&lv[vrow * 64 + c1 * 8 + (l4 & 1) * 4];
        vf[dt] = vv.v;
      }
      #pragma unroll
      for (int qt = 0; qt < 2; qt++) {
        union { unsigned int u[4]; s16x8 v; } pa;
        pa.u[0] = pw[qt][2 * ks][0];
        pa.u[1] = pw[qt][2 * ks][1];
        pa.u[2] = pw[qt][2 * ks + 1][0];
        pa.u[3] = pw[qt][2 * ks + 1][1];
        #pragma unroll
        for (int dt = 0; dt < 4; dt++)
          oacc[qt][dt] = mfma16(pa.v, vf[dt], oacc[qt][dt]);
      }
    }

    if (kt == 0)
      asm volatile("s_waitcnt vmcnt(12)" ::: "memory");
    else if (kt < 30)
      asm volatile("s_waitcnt vmcnt(20)" ::: "memory");
    else if (kt == 30)
      asm volatile("s_waitcnt vmcnt(16)" ::: "memory");
    if (kt < 31) __builtin_amdgcn_s_barrier();
  }

  const int b = bh >> 4, h = bh & 15;
  const size_t aob = ((size_t)b * SS + q0 + wv * 32) * DM + h * DK;
  #pragma unroll
  for (int qt = 0; qt < 2; qt++)
    #pragma unroll
    for (int dt = 0; dt < 4; dt++)
      #pragma unroll
      for (int r = 0; r < 4; r++)
        AOh[aob + (size_t)(qt * 16 + l4 * 4 + r) * DM + dt * 16 + l15] =
            f2bf(oacc[qt][dt][r]);
}

extern "C" void kernel_launch(void* const* d_in, const int* in_sizes, int n_in,
                              void* d_out, int out_size, void* d_ws, size_t ws_size,
                              hipStream_t stream) {
  const float* x  = (const float*)d_in[0];
  const float* Wq = (const float*)d_in[1];
  const float* bq = (const float*)d_in[2];
  const float* Wk = (const float*)d_in[3];
  const float* bk = (const float*)d_in[4];
  const float* Wv = (const float*)d_in[5];
  const float* bv = (const float*)d_in[6];
  const float* Wo = (const float*)d_in[7];
  const float* bo = (const float*)d_in[8];

  char* ws = (char*)d_ws;
  unsigned short* xh    = (unsigned short*)(ws);
  unsigned short* WTqkv = (unsigned short*)(ws + 16777216);
  unsigned short* WTo   = (unsigned short*)(ws + 16777216 + 6291456);
  unsigned short* Qh    = (unsigned short*)(ws + 25165824);
  unsigned short* Kh    = (unsigned short*)(ws + 25165824 + 1 * 16777216);
  unsigned short* VhT   = (unsigned short*)(ws + 25165824 + 2 * 16777216);
  unsigned short* AOh   = xh;  // alias: x_bf16 dead after projections

  float* outO  = (float*)d_out;
  float* attnO = (float*)d_out + (size_t)NB * SS * DM;

  k_cvt_x<<<8192, 256, 0, stream>>>(x, xh);
  dim3 tb(32, 8), tg(32, 32, 4);
  k_cvt_w4<<<tg, tb, 0, stream>>>(Wq, Wk, Wv, Wo, WTqkv, WTo);

  dim3 pq(24, 64);
  k_proj_qkv<<<pq, 256, 0, stream>>>(xh, WTqkv, bq, bk, bv, Qh, Kh, VhT);

  k_attn<<<1024, 256, 0, stream>>>(Qh, Kh, VhT, attnO, AOh);

  dim3 po(8, 64);
  k_proj_o<<<po, 256, 0, stream>>>(AOh, WTo, bo, outO);
}

// Round 16
// 551.189 us; speedup vs baseline: 1.0409x; 1.0409x over previous
//
#include <hip/hip_runtime.h>
#include <stdint.h>

#define DM 1024
#define NH 16
#define DK 64
#define NB 4
#define SS 2048

// Q pre-scale: (1/sqrt(64)) * log2(e) so scores are in log2 domain.
#define QSCALE 0.18033688011112042f

typedef float f32x4 __attribute__((ext_vector_type(4)));
typedef short s16x8 __attribute__((ext_vector_type(8)));

typedef __attribute__((address_space(1))) unsigned int glb_u32;
typedef __attribute__((address_space(3))) unsigned int lds_u32;

static __device__ __forceinline__ void gload16(const void* g, void* lds) {
  __builtin_amdgcn_global_load_lds((glb_u32*)g, (lds_u32*)lds, 16, 0, 0);
}

static __device__ __forceinline__ unsigned short f2bf(float f) {
  union { float f; unsigned int u; } v;
  v.f = f;
  unsigned int u = v.u + 0x7fffu + ((v.u >> 16) & 1u);  // RNE
  return (unsigned short)(u >> 16);
}

static __device__ __forceinline__ unsigned int cvtpk(float lo, float hi) {
  unsigned int r;
  asm("v_cvt_pk_bf16_f32 %0, %1, %2" : "=v"(r) : "v"(lo), "v"(hi));
  return r;
}

// Bare hardware 2^x / log2(x) via compiler-known builtins.
static __device__ __forceinline__ float vexp2(float x) {
  return __builtin_amdgcn_exp2f(x);
}
static __device__ __forceinline__ float vlog2(float x) {
  return __builtin_amdgcn_logf(x);
}

static __device__ __forceinline__ f32x4 mfma16(s16x8 a, s16x8 b, f32x4 c) {
  return __builtin_amdgcn_mfma_f32_16x16x32_bf16(a, b, c, 0, 0, 0);
}

// ---------------- convert x (fp32 -> bf16), 4 elems/thread ----------------
__global__ __launch_bounds__(256) void k_cvt_x(const float* __restrict__ x,
                                               unsigned short* __restrict__ xh) {
  int i = blockIdx.x * 256 + threadIdx.x;
  float4 v = ((const float4*)x)[i];
  ushort4 h;
  h.x = f2bf(v.x); h.y = f2bf(v.y); h.z = f2bf(v.z); h.w = f2bf(v.w);
  ((ushort4*)xh)[i] = h;
}

// ------- transpose-convert 4 weights in one launch (z selects W) -------
__global__ void k_cvt_w4(const float* __restrict__ Wq, const float* __restrict__ Wk,
                         const float* __restrict__ Wv, const float* __restrict__ Wo,
                         unsigned short* __restrict__ WTqkv,
                         unsigned short* __restrict__ WTo) {
  __shared__ float t[32][33];
  int z = blockIdx.z;
  const float* W = z == 0 ? Wq : (z == 1 ? Wk : (z == 2 ? Wv : Wo));
  unsigned short* dst = z < 3 ? WTqkv + (size_t)z * 1024 * 1024 : WTo;
  int tx = threadIdx.x, ty = threadIdx.y;          // 32 x 8
  int bx = blockIdx.x * 32, by = blockIdx.y * 32;  // bx: out cols, by: in rows
  #pragma unroll
  for (int i = 0; i < 4; i++)
    t[ty + 8 * i][tx] = W[(size_t)(by + ty + 8 * i) * DM + bx + tx];
  __syncthreads();
  #pragma unroll
  for (int i = 0; i < 4; i++)
    dst[(size_t)(bx + ty + 8 * i) * DM + by + tx] = f2bf(t[tx][ty + 8 * i]);
}

// ---------------- 128x128 GEMM core (shared by both proj kernels) ----------------
static __device__ __forceinline__ void gemm_core(const unsigned short* __restrict__ A,
                                                 const unsigned short* __restrict__ BT,
                                                 unsigned short* lA, unsigned short* lB,
                                                 f32x4 acc[4][4], int bm, int bn) {
  const int tid = threadIdx.x;
  const int lane = tid & 63, wv = tid >> 6;
  const int wy = wv >> 1, wx = wv & 1;
  const int l15 = lane & 15, l4 = lane >> 4;

  for (int k0 = 0; k0 < DM; k0 += 32) {
    #pragma unroll
    for (int r = 0; r < 2; r++) {
      int chunk = r * 256 + tid;
      int row = chunk >> 2, c4 = chunk & 3;  // [128 rows][32 cols], 16B chunks
      gload16(A + (size_t)(bm + row) * DM + k0 + c4 * 8,
              (char*)lA + (r * 256 + wv * 64) * 16);
      gload16(BT + (size_t)(bn + row) * DM + k0 + c4 * 8,
              (char*)lB + (r * 256 + wv * 64) * 16);
    }
    __syncthreads();
    s16x8 af[4], bf[4];
    #pragma unroll
    for (int i = 0; i < 4; i++)
      af[i] = *(const s16x8*)&lA[(wy * 64 + i * 16 + l15) * 32 + l4 * 8];
    #pragma unroll
    for (int j = 0; j < 4; j++)
      bf[j] = *(const s16x8*)&lB[(wx * 64 + j * 16 + l15) * 32 + l4 * 8];
    #pragma unroll
    for (int i = 0; i < 4; i++)
      #pragma unroll
      for (int j = 0; j < 4; j++)
        acc[i][j] = mfma16(af[i], bf[j], acc[i][j]);
    __syncthreads();
  }
}

// Fused QKV projection: BT = stacked [3072 out][1024 in]; grid (24, 64).
__global__ __launch_bounds__(256) void k_proj_qkv(
    const unsigned short* __restrict__ A, const unsigned short* __restrict__ BT,
    const float* __restrict__ bq, const float* __restrict__ bk,
    const float* __restrict__ bv, unsigned short* __restrict__ Qh,
    unsigned short* __restrict__ Kh, unsigned short* __restrict__ VhT) {
  __shared__ unsigned short lA[128 * 32];
  __shared__ unsigned short lB[128 * 32];
  const int tid = threadIdx.x;
  const int lane = tid & 63, wv = tid >> 6;
  const int wy = wv >> 1, wx = wv & 1;
  const int l15 = lane & 15, l4 = lane >> 4;
  const int bm = blockIdx.y * 128, bn = blockIdx.x * 128;

  const f32x4 fz = {0.f, 0.f, 0.f, 0.f};
  f32x4 acc[4][4];
  #pragma unroll
  for (int i = 0; i < 4; i++)
    #pragma unroll
    for (int j = 0; j < 4; j++) acc[i][j] = fz;

  gemm_core(A, BT, lA, lB, acc, bm, bn);

  // C/D: col = lane&15, row = (lane>>4)*4 + reg
  #pragma unroll
  for (int j = 0; j < 4; j++) {
    int c = bn + wx * 64 + j * 16 + l15;
    float bvv = c < 1024 ? bq[c] : (c < 2048 ? bk[c - 1024] : bv[c - 2048]);
    int cc = c & 1023, h = cc >> 6, d = cc & 63, proj = c >> 10;
    #pragma unroll
    for (int i = 0; i < 4; i++) {
      int rbase = bm + wy * 64 + i * 16 + l4 * 4;
      #pragma unroll
      for (int r = 0; r < 4; r++) {
        float v = acc[i][j][r] + bvv;
        int row = rbase + r;
        int b = row >> 11, s = row & 2047;
        size_t qk = (((size_t)(b * NH + h)) * SS + s) * DK + d;
        if (proj == 0)
          Qh[qk] = f2bf(v * QSCALE);
        else if (proj == 1)
          Kh[qk] = f2bf(v);
        else
          VhT[(((size_t)(b * NH + h)) * DK + d) * SS + s] = f2bf(v);
      }
    }
  }
}

// Output projection: fp32 out, nt stores.
__global__ __launch_bounds__(256) void k_proj_o(const unsigned short* __restrict__ A,
                                                const unsigned short* __restrict__ BT,
                                                const float* __restrict__ bias,
                                                float* __restrict__ outp) {
  __shared__ unsigned short lA[128 * 32];
  __shared__ unsigned short lB[128 * 32];
  const int tid = threadIdx.x;
  const int lane = tid & 63, wv = tid >> 6;
  const int wy = wv >> 1, wx = wv & 1;
  const int l15 = lane & 15, l4 = lane >> 4;
  const int bm = blockIdx.y * 128, bn = blockIdx.x * 128;

  const f32x4 fz = {0.f, 0.f, 0.f, 0.f};
  f32x4 acc[4][4];
  #pragma unroll
  for (int i = 0; i < 4; i++)
    #pragma unroll
    for (int j = 0; j < 4; j++) acc[i][j] = fz;

  gemm_core(A, BT, lA, lB, acc, bm, bn);

  #pragma unroll
  for (int j = 0; j < 4; j++) {
    int c = bn + wx * 64 + j * 16 + l15;
    float bvv = bias[c];
    #pragma unroll
    for (int i = 0; i < 4; i++) {
      int rbase = bm + wy * 64 + i * 16 + l4 * 4;
      #pragma unroll
      for (int r = 0; r < 4; r++) {
        float v = acc[i][j][r] + bvv;
        __builtin_nontemporal_store(v, outp + (size_t)(rbase + r) * DM + c);
      }
    }
  }
}

// ---------------- fused attention, KVBLK=64, XCD-pinned heads ----------------
// PROBE BUILD: pass A repeated 4x (REP) with 6-slot ring + 3-deep prefetch.
// Pass B identical to round-14 best. k_attn's own counter row yields
// A_new = (dur_row - 200us)/4 plus pass-A's FETCH/VALU/Mfma/Occupancy regime.
__global__ __launch_bounds__(256, 3) void k_attn(const unsigned short* __restrict__ Qh,
                                                 const unsigned short* __restrict__ Kh,
                                                 const unsigned short* __restrict__ VhT,
                                                 float* __restrict__ attnO,
                                                 unsigned short* __restrict__ AOh) {
  __shared__ unsigned short sm[24576];

  const int tid = threadIdx.x;
  const int lane = tid & 63, wv = tid >> 6;
  const int l15 = lane & 15, l4 = lane >> 4;
  const int bid = blockIdx.x;
  const int xcd = bid & 7, t = bid >> 3;
  const int bh = ((t >> 4) << 3) | xcd;
  const int q0 = (t & 15) * 128;
  const size_t kbase = (size_t)bh * SS * DK;
  const f32x4 fz = {0.f, 0.f, 0.f, 0.f};

  auto stageK = [&](int kt, unsigned short* dst) {
    #pragma unroll
    for (int r = 0; r < 2; r++) {
      int chunk = r * 256 + tid;
      int row = chunk >> 3, c = chunk & 7;
      int cs = c ^ (row & 7);
      gload16(Kh + kbase + (size_t)(kt * 64 + row) * DK + cs * 8,
              (char*)dst + (r * 256 + wv * 64) * 16);
    }
  };
  auto stageV = [&](int kt, unsigned short* dst) {
    #pragma unroll
    for (int r = 0; r < 2; r++) {
      int chunk = r * 256 + tid;
      int row = chunk >> 3, c = chunk & 7;
      int cs = c ^ (row & 7);
      gload16(VhT + kbase + (size_t)row * SS + kt * 64 + cs * 8,
              (char*)dst + (r * 256 + wv * 64) * 16);
    }
  };

  s16x8 qf[2][2];
  #pragma unroll
  for (int qt = 0; qt < 2; qt++)
    #pragma unroll
    for (int ks = 0; ks < 2; ks++) {
      int row = q0 + wv * 32 + qt * 16 + l15;
      qf[qt][ks] = *(const s16x8*)&Qh[kbase + (size_t)row * DK + ks * 32 + l4 * 8];
    }

  // ---- Pass A (REP=4 probe): 6-slot ring, 3-deep prefetch ----
  float lsA[2];
  for (int rep = 0; rep < 4; rep++) {
    lsA[0] = 0.f;
    lsA[1] = 0.f;
    __builtin_amdgcn_s_barrier();  // prior rep's readers done with ring slots
    stageK(0, sm);
    stageK(1, sm + 4096);
    stageK(2, sm + 8192);
    asm volatile("s_waitcnt vmcnt(4)" ::: "memory");
    __builtin_amdgcn_s_barrier();
    for (int kt = 0; kt < 32; kt++) {
      const unsigned short* kb = sm + (kt % 6) * 4096;
      if (kt < 29) stageK(kt + 3, sm + ((kt + 3) % 6) * 4096);
      #pragma unroll
      for (int nt = 0; nt < 4; nt++) {
        int krow = nt * 16 + l15;
        s16x8 kf0 = *(const s16x8*)&kb[krow * 64 + ((l4) ^ (krow & 7)) * 8];
        s16x8 kf1 = *(const s16x8*)&kb[krow * 64 + ((4 + l4) ^ (krow & 7)) * 8];
        #pragma unroll
        for (int qt = 0; qt < 2; qt++) {
          f32x4 s = fz;
          s = mfma16(kf0, qf[qt][0], s);
          s = mfma16(kf1, qf[qt][1], s);
          lsA[qt] += vexp2(s[0]) + vexp2(s[1]) + vexp2(s[2]) + vexp2(s[3]);
        }
      }
      if (kt < 29)
        asm volatile("s_waitcnt vmcnt(4)" ::: "memory");
      else if (kt == 29)
        asm volatile("s_waitcnt vmcnt(2)" ::: "memory");
      else if (kt == 30)
        asm volatile("s_waitcnt vmcnt(0)" ::: "memory");
      if (kt < 31) __builtin_amdgcn_s_barrier();
    }
  }

  float l2l[2];
  #pragma unroll
  for (int qt = 0; qt < 2; qt++) {
    float v = lsA[qt];
    v += __shfl_xor(v, 16);
    v += __shfl_xor(v, 32);
    l2l[qt] = -vlog2(v);  // p = 2^(s + l2l)
  }

  // ---- Pass B (unchanged from round-14 best) ----
  f32x4 oacc[2][4];
  #pragma unroll
  for (int qt = 0; qt < 2; qt++)
    #pragma unroll
    for (int dt = 0; dt < 4; dt++) oacc[qt][dt] = fz;

  float* ap0 = attnO + ((size_t)bh * SS + q0 + wv * 32 + l15) * SS;
  float* ap1 = ap0 + (size_t)16 * SS;

  __builtin_amdgcn_s_barrier();  // pass-A readers done before restaging
  stageK(0, sm);
  stageV(0, sm + 12288);
  stageK(1, sm + 4096);
  stageV(1, sm + 12288 + 4096);
  asm volatile("s_waitcnt vmcnt(4)" ::: "memory");
  __builtin_amdgcn_s_barrier();

  for (int kt = 0; kt < 32; kt++) {
    int sl = kt % 3;
    const unsigned short* lk = sm + sl * 4096;
    const unsigned short* lv = sm + 12288 + sl * 4096;
    if (kt < 30) {
      int s2 = (kt + 2) % 3;
      stageK(kt + 2, sm + s2 * 4096);
      stageV(kt + 2, sm + 12288 + s2 * 4096);
    }
    __builtin_amdgcn_sched_barrier(0);

    unsigned int pw[2][4][2];
    #pragma unroll
    for (int nt = 0; nt < 4; nt++) {
      int krow = nt * 16 + l15;
      s16x8 kf0 = *(const s16x8*)&lk[krow * 64 + ((l4) ^ (krow & 7)) * 8];
      s16x8 kf1 = *(const s16x8*)&lk[krow * 64 + ((4 + l4) ^ (krow & 7)) * 8];
      #pragma unroll
      for (int qt = 0; qt < 2; qt++) {
        f32x4 s = fz;
        s = mfma16(kf0, qf[qt][0], s);
        s = mfma16(kf1, qf[qt][1], s);
        f32x4 p;
        p[0] = vexp2(s[0] + l2l[qt]);
        p[1] = vexp2(s[1] + l2l[qt]);
        p[2] = vexp2(s[2] + l2l[qt]);
        p[3] = vexp2(s[3] + l2l[qt]);
        float* ap = (qt == 0 ? ap0 : ap1) + kt * 64 + nt * 16 + l4 * 4;
        __builtin_nontemporal_store(p, (f32x4*)ap);
        pw[qt][nt][0] = cvtpk(p[0], p[1]);
        pw[qt][nt][1] = cvtpk(p[2], p[3]);
      }
    }

    #pragma unroll
    for (int ks = 0; ks < 2; ks++) {
      s16x8 vf[4];
      #pragma unroll
      for (int dt = 0; dt < 4; dt++) {
        int vrow = dt * 16 + l15;
        int c0 = (4 * ks + (l4 >> 1)) ^ (vrow & 7);
        int c1 = (4 * ks + 2 + (l4 >> 1)) ^ (vrow & 7);
        union { unsigned long long q[2]; s16x8 v; } vv;
        vv.q[0] = *(const unsigned long long*)&lv[vrow * 64 + c0 * 8 + (l4 & 1) * 4];
        vv.q[1] = *(const unsigned long long*)&lv[vrow * 64 + c1 * 8 + (l4 & 1) * 4];
        vf[dt] = vv.v;
      }
      #pragma unroll
      for (int qt = 0; qt < 2; qt++) {
        union { unsigned int u[4]; s16x8 v; } pa;
        pa.u[0] = pw[qt][2 * ks][0];
        pa.u[1] = pw[qt][2 * ks][1];
        pa.u[2] = pw[qt][2 * ks + 1][0];
        pa.u[3] = pw[qt][2 * ks + 1][1];
        #pragma unroll
        for (int dt = 0; dt < 4; dt++)
          oacc[qt][dt] = mfma16(pa.v, vf[dt], oacc[qt][dt]);
      }
    }

    if (kt == 0)
      asm volatile("s_waitcnt vmcnt(12)" ::: "memory");
    else if (kt < 30)
      asm volatile("s_waitcnt vmcnt(20)" ::: "memory");
    else if (kt == 30)
      asm volatile("s_waitcnt vmcnt(16)" ::: "memory");
    if (kt < 31) __builtin_amdgcn_s_barrier();
  }

  const int b = bh >> 4, h = bh & 15;
  const size_t aob = ((size_t)b * SS + q0 + wv * 32) * DM + h * DK;
  #pragma unroll
  for (int qt = 0; qt < 2; qt++)
    #pragma unroll
    for (int dt = 0; dt < 4; dt++)
      #pragma unroll
      for (int r = 0; r < 4; r++)
        AOh[aob + (size_t)(qt * 16 + l4 * 4 + r) * DM + dt * 16 + l15] =
            f2bf(oacc[qt][dt][r]);
}

extern "C" void kernel_launch(void* const* d_in, const int* in_sizes, int n_in,
                              void* d_out, int out_size, void* d_ws, size_t ws_size,
                              hipStream_t stream) {
  const float* x  = (const float*)d_in[0];
  const float* Wq = (const float*)d_in[1];
  const float* bq = (const float*)d_in[2];
  const float* Wk = (const float*)d_in[3];
  const float* bk = (const float*)d_in[4];
  const float* Wv = (const float*)d_in[5];
  const float* bv = (const float*)d_in[6];
  const float* Wo = (const float*)d_in[7];
  const float* bo = (const float*)d_in[8];

  char* ws = (char*)d_ws;
  unsigned short* xh    = (unsigned short*)(ws);
  unsigned short* WTqkv = (unsigned short*)(ws + 16777216);
  unsigned short* WTo   = (unsigned short*)(ws + 16777216 + 6291456);
  unsigned short* Qh    = (unsigned short*)(ws + 25165824);
  unsigned short* Kh    = (unsigned short*)(ws + 25165824 + 1 * 16777216);
  unsigned short* VhT   = (unsigned short*)(ws + 25165824 + 2 * 16777216);
  unsigned short* AOh   = xh;  // alias: x_bf16 dead after projections

  float* outO  = (float*)d_out;
  float* attnO = (float*)d_out + (size_t)NB * SS * DM;

  k_cvt_x<<<8192, 256, 0, stream>>>(x, xh);
  dim3 tb(32, 8), tg(32, 32, 4);
  k_cvt_w4<<<tg, tb, 0, stream>>>(Wq, Wk, Wv, Wo, WTqkv, WTo);

  dim3 pq(24, 64);
  k_proj_qkv<<<pq, 256, 0, stream>>>(xh, WTqkv, bq, bk, bv, Qh, Kh, VhT);

  k_attn<<<1024, 256, 0, stream>>>(Qh, Kh, VhT, attnO, AOh);

  dim3 po(8, 64);
  k_proj_o<<<po, 256, 0, stream>>>(AOh, WTo, bo, outO);
}

// Round 17
// 505.122 us; speedup vs baseline: 1.1358x; 1.0912x over previous
//
#include <hip/hip_runtime.h>
#include <stdint.h>

#define DM 1024
#define NH 16
#define DK 64
#define NB 4
#define SS 2048

// Q pre-scale: (1/sqrt(64)) * log2(e) so scores are in log2 domain.
#define QSCALE 0.18033688011112042f

typedef float f32x4 __attribute__((ext_vector_type(4)));
typedef short s16x8 __attribute__((ext_vector_type(8)));

typedef __attribute__((address_space(1))) unsigned int glb_u32;
typedef __attribute__((address_space(3))) unsigned int lds_u32;

static __device__ __forceinline__ void gload16(const void* g, void* lds) {
  __builtin_amdgcn_global_load_lds((glb_u32*)g, (lds_u32*)lds, 16, 0, 0);
}

static __device__ __forceinline__ unsigned short f2bf(float f) {
  union { float f; unsigned int u; } v;
  v.f = f;
  unsigned int u = v.u + 0x7fffu + ((v.u >> 16) & 1u);  // RNE
  return (unsigned short)(u >> 16);
}

static __device__ __forceinline__ unsigned int cvtpk(float lo, float hi) {
  unsigned int r;
  asm("v_cvt_pk_bf16_f32 %0, %1, %2" : "=v"(r) : "v"(lo), "v"(hi));
  return r;
}

// Bare hardware 2^x / log2(x) via compiler-known builtins.
static __device__ __forceinline__ float vexp2(float x) {
  return __builtin_amdgcn_exp2f(x);
}
static __device__ __forceinline__ float vlog2(float x) {
  return __builtin_amdgcn_logf(x);
}

static __device__ __forceinline__ f32x4 mfma16(s16x8 a, s16x8 b, f32x4 c) {
  return __builtin_amdgcn_mfma_f32_16x16x32_bf16(a, b, c, 0, 0, 0);
}

// ---------------- convert x (fp32 -> bf16), 4 elems/thread ----------------
__global__ __launch_bounds__(256) void k_cvt_x(const float* __restrict__ x,
                                               unsigned short* __restrict__ xh) {
  int i = blockIdx.x * 256 + threadIdx.x;
  float4 v = ((const float4*)x)[i];
  ushort4 h;
  h.x = f2bf(v.x); h.y = f2bf(v.y); h.z = f2bf(v.z); h.w = f2bf(v.w);
  ((ushort4*)xh)[i] = h;
}

// ------- transpose-convert 4 weights in one launch (z selects W) -------
__global__ void k_cvt_w4(const float* __restrict__ Wq, const float* __restrict__ Wk,
                         const float* __restrict__ Wv, const float* __restrict__ Wo,
                         unsigned short* __restrict__ WTqkv,
                         unsigned short* __restrict__ WTo) {
  __shared__ float t[32][33];
  int z = blockIdx.z;
  const float* W = z == 0 ? Wq : (z == 1 ? Wk : (z == 2 ? Wv : Wo));
  unsigned short* dst = z < 3 ? WTqkv + (size_t)z * 1024 * 1024 : WTo;
  int tx = threadIdx.x, ty = threadIdx.y;          // 32 x 8
  int bx = blockIdx.x * 32, by = blockIdx.y * 32;  // bx: out cols, by: in rows
  #pragma unroll
  for (int i = 0; i < 4; i++)
    t[ty + 8 * i][tx] = W[(size_t)(by + ty + 8 * i) * DM + bx + tx];
  __syncthreads();
  #pragma unroll
  for (int i = 0; i < 4; i++)
    dst[(size_t)(bx + ty + 8 * i) * DM + by + tx] = f2bf(t[tx][ty + 8 * i]);
}

// ---------------- 128x128 GEMM core (shared by both proj kernels) ----------------
static __device__ __forceinline__ void gemm_core(const unsigned short* __restrict__ A,
                                                 const unsigned short* __restrict__ BT,
                                                 unsigned short* lA, unsigned short* lB,
                                                 f32x4 acc[4][4], int bm, int bn) {
  const int tid = threadIdx.x;
  const int lane = tid & 63, wv = tid >> 6;
  const int wy = wv >> 1, wx = wv & 1;
  const int l15 = lane & 15, l4 = lane >> 4;

  for (int k0 = 0; k0 < DM; k0 += 32) {
    #pragma unroll
    for (int r = 0; r < 2; r++) {
      int chunk = r * 256 + tid;
      int row = chunk >> 2, c4 = chunk & 3;  // [128 rows][32 cols], 16B chunks
      gload16(A + (size_t)(bm + row) * DM + k0 + c4 * 8,
              (char*)lA + (r * 256 + wv * 64) * 16);
      gload16(BT + (size_t)(bn + row) * DM + k0 + c4 * 8,
              (char*)lB + (r * 256 + wv * 64) * 16);
    }
    __syncthreads();
    s16x8 af[4], bf[4];
    #pragma unroll
    for (int i = 0; i < 4; i++)
      af[i] = *(const s16x8*)&lA[(wy * 64 + i * 16 + l15) * 32 + l4 * 8];
    #pragma unroll
    for (int j = 0; j < 4; j++)
      bf[j] = *(const s16x8*)&lB[(wx * 64 + j * 16 + l15) * 32 + l4 * 8];
    #pragma unroll
    for (int i = 0; i < 4; i++)
      #pragma unroll
      for (int j = 0; j < 4; j++)
        acc[i][j] = mfma16(af[i], bf[j], acc[i][j]);
    __syncthreads();
  }
}

// Fused QKV projection: BT = stacked [3072 out][1024 in]; grid (24, 64).
__global__ __launch_bounds__(256) void k_proj_qkv(
    const unsigned short* __restrict__ A, const unsigned short* __restrict__ BT,
    const float* __restrict__ bq, const float* __restrict__ bk,
    const float* __restrict__ bv, unsigned short* __restrict__ Qh,
    unsigned short* __restrict__ Kh, unsigned short* __restrict__ VhT) {
  __shared__ unsigned short lA[128 * 32];
  __shared__ unsigned short lB[128 * 32];
  const int tid = threadIdx.x;
  const int lane = tid & 63, wv = tid >> 6;
  const int wy = wv >> 1, wx = wv & 1;
  const int l15 = lane & 15, l4 = lane >> 4;
  const int bm = blockIdx.y * 128, bn = blockIdx.x * 128;

  const f32x4 fz = {0.f, 0.f, 0.f, 0.f};
  f32x4 acc[4][4];
  #pragma unroll
  for (int i = 0; i < 4; i++)
    #pragma unroll
    for (int j = 0; j < 4; j++) acc[i][j] = fz;

  gemm_core(A, BT, lA, lB, acc, bm, bn);

  // C/D: col = lane&15, row = (lane>>4)*4 + reg
  #pragma unroll
  for (int j = 0; j < 4; j++) {
    int c = bn + wx * 64 + j * 16 + l15;
    float bvv = c < 1024 ? bq[c] : (c < 2048 ? bk[c - 1024] : bv[c - 2048]);
    int cc = c & 1023, h = cc >> 6, d = cc & 63, proj = c >> 10;
    #pragma unroll
    for (int i = 0; i < 4; i++) {
      int rbase = bm + wy * 64 + i * 16 + l4 * 4;
      #pragma unroll
      for (int r = 0; r < 4; r++) {
        float v = acc[i][j][r] + bvv;
        int row = rbase + r;
        int b = row >> 11, s = row & 2047;
        size_t qk = (((size_t)(b * NH + h)) * SS + s) * DK + d;
        if (proj == 0)
          Qh[qk] = f2bf(v * QSCALE);
        else if (proj == 1)
          Kh[qk] = f2bf(v);
        else
          VhT[(((size_t)(b * NH + h)) * DK + d) * SS + s] = f2bf(v);
      }
    }
  }
}

// Output projection: fp32 out, nt stores.
__global__ __launch_bounds__(256) void k_proj_o(const unsigned short* __restrict__ A,
                                                const unsigned short* __restrict__ BT,
                                                const float* __restrict__ bias,
                                                float* __restrict__ outp) {
  __shared__ unsigned short lA[128 * 32];
  __shared__ unsigned short lB[128 * 32];
  const int tid = threadIdx.x;
  const int lane = tid & 63, wv = tid >> 6;
  const int wy = wv >> 1, wx = wv & 1;
  const int l15 = lane & 15, l4 = lane >> 4;
  const int bm = blockIdx.y * 128, bn = blockIdx.x * 128;

  const f32x4 fz = {0.f, 0.f, 0.f, 0.f};
  f32x4 acc[4][4];
  #pragma unroll
  for (int i = 0; i < 4; i++)
    #pragma unroll
    for (int j = 0; j < 4; j++) acc[i][j] = fz;

  gemm_core(A, BT, lA, lB, acc, bm, bn);

  #pragma unroll
  for (int j = 0; j < 4; j++) {
    int c = bn + wx * 64 + j * 16 + l15;
    float bvv = bias[c];
    #pragma unroll
    for (int i = 0; i < 4; i++) {
      int rbase = bm + wy * 64 + i * 16 + l4 * 4;
      #pragma unroll
      for (int r = 0; r < 4; r++) {
        float v = acc[i][j][r] + bvv;
        __builtin_nontemporal_store(v, outp + (size_t)(rbase + r) * DM + c);
      }
    }
  }
}

// ---------------- fused attention, KVBLK=64, XCD-pinned heads ----------------
// Pass A: 6-slot K ring, 3-deep prefetch (covers ~900cy load latency) —
// measured ~59us vs ~190us at 2-deep (R16 probe). Pass B: round-14 best
// (triple-buffered, counted vmcnt never waits on stores, nt P stores).
__global__ __launch_bounds__(256, 3) void k_attn(const unsigned short* __restrict__ Qh,
                                                 const unsigned short* __restrict__ Kh,
                                                 const unsigned short* __restrict__ VhT,
                                                 float* __restrict__ attnO,
                                                 unsigned short* __restrict__ AOh) {
  __shared__ unsigned short sm[24576];

  const int tid = threadIdx.x;
  const int lane = tid & 63, wv = tid >> 6;
  const int l15 = lane & 15, l4 = lane >> 4;
  const int bid = blockIdx.x;
  const int xcd = bid & 7, t = bid >> 3;
  const int bh = ((t >> 4) << 3) | xcd;
  const int q0 = (t & 15) * 128;
  const size_t kbase = (size_t)bh * SS * DK;
  const f32x4 fz = {0.f, 0.f, 0.f, 0.f};

  auto stageK = [&](int kt, unsigned short* dst) {
    #pragma unroll
    for (int r = 0; r < 2; r++) {
      int chunk = r * 256 + tid;
      int row = chunk >> 3, c = chunk & 7;
      int cs = c ^ (row & 7);
      gload16(Kh + kbase + (size_t)(kt * 64 + row) * DK + cs * 8,
              (char*)dst + (r * 256 + wv * 64) * 16);
    }
  };
  auto stageV = [&](int kt, unsigned short* dst) {
    #pragma unroll
    for (int r = 0; r < 2; r++) {
      int chunk = r * 256 + tid;
      int row = chunk >> 3, c = chunk & 7;
      int cs = c ^ (row & 7);
      gload16(VhT + kbase + (size_t)row * SS + kt * 64 + cs * 8,
              (char*)dst + (r * 256 + wv * 64) * 16);
    }
  };

  s16x8 qf[2][2];
  #pragma unroll
  for (int qt = 0; qt < 2; qt++)
    #pragma unroll
    for (int ks = 0; ks < 2; ks++) {
      int row = q0 + wv * 32 + qt * 16 + l15;
      qf[qt][ks] = *(const s16x8*)&Qh[kbase + (size_t)row * DK + ks * 32 + l4 * 8];
    }

  // ---- Pass A: 6-slot ring, 3-deep prefetch ----
  float lsA[2] = {0.f, 0.f};
  stageK(0, sm);
  stageK(1, sm + 4096);
  stageK(2, sm + 8192);
  asm volatile("s_waitcnt vmcnt(4)" ::: "memory");
  __builtin_amdgcn_s_barrier();
  for (int kt = 0; kt < 32; kt++) {
    const unsigned short* kb = sm + (kt % 6) * 4096;
    if (kt < 29) stageK(kt + 3, sm + ((kt + 3) % 6) * 4096);
    #pragma unroll
    for (int nt = 0; nt < 4; nt++) {
      int krow = nt * 16 + l15;
      s16x8 kf0 = *(const s16x8*)&kb[krow * 64 + ((l4) ^ (krow & 7)) * 8];
      s16x8 kf1 = *(const s16x8*)&kb[krow * 64 + ((4 + l4) ^ (krow & 7)) * 8];
      #pragma unroll
      for (int qt = 0; qt < 2; qt++) {
        f32x4 s = fz;
        s = mfma16(kf0, qf[qt][0], s);
        s = mfma16(kf1, qf[qt][1], s);
        lsA[qt] += vexp2(s[0]) + vexp2(s[1]) + vexp2(s[2]) + vexp2(s[3]);
      }
    }
    if (kt < 29)
      asm volatile("s_waitcnt vmcnt(4)" ::: "memory");
    else if (kt == 29)
      asm volatile("s_waitcnt vmcnt(2)" ::: "memory");
    else if (kt == 30)
      asm volatile("s_waitcnt vmcnt(0)" ::: "memory");
    if (kt < 31) __builtin_amdgcn_s_barrier();
  }

  float l2l[2];
  #pragma unroll
  for (int qt = 0; qt < 2; qt++) {
    float v = lsA[qt];
    v += __shfl_xor(v, 16);
    v += __shfl_xor(v, 32);
    l2l[qt] = -vlog2(v);  // p = 2^(s + l2l)
  }

  // ---- Pass B (round-14 best) ----
  f32x4 oacc[2][4];
  #pragma unroll
  for (int qt = 0; qt < 2; qt++)
    #pragma unroll
    for (int dt = 0; dt < 4; dt++) oacc[qt][dt] = fz;

  float* ap0 = attnO + ((size_t)bh * SS + q0 + wv * 32 + l15) * SS;
  float* ap1 = ap0 + (size_t)16 * SS;

  __builtin_amdgcn_s_barrier();  // pass-A readers done before restaging
  stageK(0, sm);
  stageV(0, sm + 12288);
  stageK(1, sm + 4096);
  stageV(1, sm + 12288 + 4096);
  asm volatile("s_waitcnt vmcnt(4)" ::: "memory");
  __builtin_amdgcn_s_barrier();

  for (int kt = 0; kt < 32; kt++) {
    int sl = kt % 3;
    const unsigned short* lk = sm + sl * 4096;
    const unsigned short* lv = sm + 12288 + sl * 4096;
    if (kt < 30) {
      int s2 = (kt + 2) % 3;
      stageK(kt + 2, sm + s2 * 4096);
      stageV(kt + 2, sm + 12288 + s2 * 4096);
    }
    __builtin_amdgcn_sched_barrier(0);

    unsigned int pw[2][4][2];
    #pragma unroll
    for (int nt = 0; nt < 4; nt++) {
      int krow = nt * 16 + l15;
      s16x8 kf0 = *(const s16x8*)&lk[krow * 64 + ((l4) ^ (krow & 7)) * 8];
      s16x8 kf1 = *(const s16x8*)&lk[krow * 64 + ((4 + l4) ^ (krow & 7)) * 8];
      #pragma unroll
      for (int qt = 0; qt < 2; qt++) {
        f32x4 s = fz;
        s = mfma16(kf0, qf[qt][0], s);
        s = mfma16(kf1, qf[qt][1], s);
        f32x4 p;
        p[0] = vexp2(s[0] + l2l[qt]);
        p[1] = vexp2(s[1] + l2l[qt]);
        p[2] = vexp2(s[2] + l2l[qt]);
        p[3] = vexp2(s[3] + l2l[qt]);
        float* ap = (qt == 0 ? ap0 : ap1) + kt * 64 + nt * 16 + l4 * 4;
        __builtin_nontemporal_store(p, (f32x4*)ap);
        pw[qt][nt][0] = cvtpk(p[0], p[1]);
        pw[qt][nt][1] = cvtpk(p[2], p[3]);
      }
    }

    #pragma unroll
    for (int ks = 0; ks < 2; ks++) {
      s16x8 vf[4];
      #pragma unroll
      for (int dt = 0; dt < 4; dt++) {
        int vrow = dt * 16 + l15;
        int c0 = (4 * ks + (l4 >> 1)) ^ (vrow & 7);
        int c1 = (4 * ks + 2 + (l4 >> 1)) ^ (vrow & 7);
        union { unsigned long long q[2]; s16x8 v; } vv;
        vv.q[0] = *(const unsigned long long*)&lv[vrow * 64 + c0 * 8 + (l4 & 1) * 4];
        vv.q[1] = *(const unsigned long long*)&lv[vrow * 64 + c1 * 8 + (l4 & 1) * 4];
        vf[dt] = vv.v;
      }
      #pragma unroll
      for (int qt = 0; qt < 2; qt++) {
        union { unsigned int u[4]; s16x8 v; } pa;
        pa.u[0] = pw[qt][2 * ks][0];
        pa.u[1] = pw[qt][2 * ks][1];
        pa.u[2] = pw[qt][2 * ks + 1][0];
        pa.u[3] = pw[qt][2 * ks + 1][1];
        #pragma unroll
        for (int dt = 0; dt < 4; dt++)
          oacc[qt][dt] = mfma16(pa.v, vf[dt], oacc[qt][dt]);
      }
    }

    if (kt == 0)
      asm volatile("s_waitcnt vmcnt(12)" ::: "memory");
    else if (kt < 30)
      asm volatile("s_waitcnt vmcnt(20)" ::: "memory");
    else if (kt == 30)
      asm volatile("s_waitcnt vmcnt(16)" ::: "memory");
    if (kt < 31) __builtin_amdgcn_s_barrier();
  }

  const int b = bh >> 4, h = bh & 15;
  const size_t aob = ((size_t)b * SS + q0 + wv * 32) * DM + h * DK;
  #pragma unroll
  for (int qt = 0; qt < 2; qt++)
    #pragma unroll
    for (int dt = 0; dt < 4; dt++)
      #pragma unroll
      for (int r = 0; r < 4; r++)
        AOh[aob + (size_t)(qt * 16 + l4 * 4 + r) * DM + dt * 16 + l15] =
            f2bf(oacc[qt][dt][r]);
}

extern "C" void kernel_launch(void* const* d_in, const int* in_sizes, int n_in,
                              void* d_out, int out_size, void* d_ws, size_t ws_size,
                              hipStream_t stream) {
  const float* x  = (const float*)d_in[0];
  const float* Wq = (const float*)d_in[1];
  const float* bq = (const float*)d_in[2];
  const float* Wk = (const float*)d_in[3];
  const float* bk = (const float*)d_in[4];
  const float* Wv = (const float*)d_in[5];
  const float* bv = (const float*)d_in[6];
  const float* Wo = (const float*)d_in[7];
  const float* bo = (const float*)d_in[8];

  char* ws = (char*)d_ws;
  unsigned short* xh    = (unsigned short*)(ws);
  unsigned short* WTqkv = (unsigned short*)(ws + 16777216);
  unsigned short* WTo   = (unsigned short*)(ws + 16777216 + 6291456);
  unsigned short* Qh    = (unsigned short*)(ws + 25165824);
  unsigned short* Kh    = (unsigned short*)(ws + 25165824 + 1 * 16777216);
  unsigned short* VhT   = (unsigned short*)(ws + 25165824 + 2 * 16777216);
  unsigned short* AOh   = xh;  // alias: x_bf16 dead after projections

  float* outO  = (float*)d_out;
  float* attnO = (float*)d_out + (size_t)NB * SS * DM;

  k_cvt_x<<<8192, 256, 0, stream>>>(x, xh);
  dim3 tb(32, 8), tg(32, 32, 4);
  k_cvt_w4<<<tg, tb, 0, stream>>>(Wq, Wk, Wv, Wo, WTqkv, WTo);

  dim3 pq(24, 64);
  k_proj_qkv<<<pq, 256, 0, stream>>>(xh, WTqkv, bq, bk, bv, Qh, Kh, VhT);

  k_attn<<<1024, 256, 0, stream>>>(Qh, Kh, VhT, attnO, AOh);

  dim3 po(8, 64);
  k_proj_o<<<po, 256, 0, stream>>>(AOh, WTo, bo, outO);
}

// Round 18
// 436.104 us; speedup vs baseline: 1.3156x; 1.1583x over previous
//
#include <hip/hip_runtime.h>
#include <stdint.h>

#define DM 1024
#define NH 16
#define DK 64
#define NB 4
#define SS 2048

// Q pre-scale: (1/sqrt(64)) * log2(e) so scores are in log2 domain.
#define QSCALE 0.18033688011112042f

typedef float f32x4 __attribute__((ext_vector_type(4)));
typedef short s16x8 __attribute__((ext_vector_type(8)));

typedef __attribute__((address_space(1))) unsigned int glb_u32;
typedef __attribute__((address_space(3))) unsigned int lds_u32;

static __device__ __forceinline__ void gload16(const void* g, void* lds) {
  __builtin_amdgcn_global_load_lds((glb_u32*)g, (lds_u32*)lds, 16, 0, 0);
}

static __device__ __forceinline__ unsigned short f2bf(float f) {
  union { float f; unsigned int u; } v;
  v.f = f;
  unsigned int u = v.u + 0x7fffu + ((v.u >> 16) & 1u);  // RNE
  return (unsigned short)(u >> 16);
}

static __device__ __forceinline__ unsigned int cvtpk(float lo, float hi) {
  unsigned int r;
  asm("v_cvt_pk_bf16_f32 %0, %1, %2" : "=v"(r) : "v"(lo), "v"(hi));
  return r;
}

// Bare hardware 2^x / log2(x) via compiler-known builtins.
static __device__ __forceinline__ float vexp2(float x) {
  return __builtin_amdgcn_exp2f(x);
}
static __device__ __forceinline__ float vlog2(float x) {
  return __builtin_amdgcn_logf(x);
}

static __device__ __forceinline__ f32x4 mfma16(s16x8 a, s16x8 b, f32x4 c) {
  return __builtin_amdgcn_mfma_f32_16x16x32_bf16(a, b, c, 0, 0, 0);
}

// ---------------- convert x (fp32 -> bf16), 4 elems/thread ----------------
__global__ __launch_bounds__(256) void k_cvt_x(const float* __restrict__ x,
                                               unsigned short* __restrict__ xh) {
  int i = blockIdx.x * 256 + threadIdx.x;
  float4 v = ((const float4*)x)[i];
  ushort4 h;
  h.x = f2bf(v.x); h.y = f2bf(v.y); h.z = f2bf(v.z); h.w = f2bf(v.w);
  ((ushort4*)xh)[i] = h;
}

// ------- transpose-convert 4 weights in one launch (z selects W) -------
__global__ void k_cvt_w4(const float* __restrict__ Wq, const float* __restrict__ Wk,
                         const float* __restrict__ Wv, const float* __restrict__ Wo,
                         unsigned short* __restrict__ WTqkv,
                         unsigned short* __restrict__ WTo) {
  __shared__ float t[32][33];
  int z = blockIdx.z;
  const float* W = z == 0 ? Wq : (z == 1 ? Wk : (z == 2 ? Wv : Wo));
  unsigned short* dst = z < 3 ? WTqkv + (size_t)z * 1024 * 1024 : WTo;
  int tx = threadIdx.x, ty = threadIdx.y;          // 32 x 8
  int bx = blockIdx.x * 32, by = blockIdx.y * 32;  // bx: out cols, by: in rows
  #pragma unroll
  for (int i = 0; i < 4; i++)
    t[ty + 8 * i][tx] = W[(size_t)(by + ty + 8 * i) * DM + bx + tx];
  __syncthreads();
  #pragma unroll
  for (int i = 0; i < 4; i++)
    dst[(size_t)(bx + ty + 8 * i) * DM + by + tx] = f2bf(t[tx][ty + 8 * i]);
}

// ---------------- 128x128 GEMM core (shared by both proj kernels) ----------------
static __device__ __forceinline__ void gemm_core(const unsigned short* __restrict__ A,
                                                 const unsigned short* __restrict__ BT,
                                                 unsigned short* lA, unsigned short* lB,
                                                 f32x4 acc[4][4], int bm, int bn) {
  const int tid = threadIdx.x;
  const int lane = tid & 63, wv = tid >> 6;
  const int wy = wv >> 1, wx = wv & 1;
  const int l15 = lane & 15, l4 = lane >> 4;

  for (int k0 = 0; k0 < DM; k0 += 32) {
    #pragma unroll
    for (int r = 0; r < 2; r++) {
      int chunk = r * 256 + tid;
      int row = chunk >> 2, c4 = chunk & 3;  // [128 rows][32 cols], 16B chunks
      gload16(A + (size_t)(bm + row) * DM + k0 + c4 * 8,
              (char*)lA + (r * 256 + wv * 64) * 16);
      gload16(BT + (size_t)(bn + row) * DM + k0 + c4 * 8,
              (char*)lB + (r * 256 + wv * 64) * 16);
    }
    __syncthreads();
    s16x8 af[4], bf[4];
    #pragma unroll
    for (int i = 0; i < 4; i++)
      af[i] = *(const s16x8*)&lA[(wy * 64 + i * 16 + l15) * 32 + l4 * 8];
    #pragma unroll
    for (int j = 0; j < 4; j++)
      bf[j] = *(const s16x8*)&lB[(wx * 64 + j * 16 + l15) * 32 + l4 * 8];
    #pragma unroll
    for (int i = 0; i < 4; i++)
      #pragma unroll
      for (int j = 0; j < 4; j++)
        acc[i][j] = mfma16(af[i], bf[j], acc[i][j]);
    __syncthreads();
  }
}

// Fused QKV projection: BT = stacked [3072 out][1024 in]; grid (24, 64).
__global__ __launch_bounds__(256) void k_proj_qkv(
    const unsigned short* __restrict__ A, const unsigned short* __restrict__ BT,
    const float* __restrict__ bq, const float* __restrict__ bk,
    const float* __restrict__ bv, unsigned short* __restrict__ Qh,
    unsigned short* __restrict__ Kh, unsigned short* __restrict__ VhT) {
  __shared__ unsigned short lA[128 * 32];
  __shared__ unsigned short lB[128 * 32];
  const int tid = threadIdx.x;
  const int lane = tid & 63, wv = tid >> 6;
  const int wy = wv >> 1, wx = wv & 1;
  const int l15 = lane & 15, l4 = lane >> 4;
  const int bm = blockIdx.y * 128, bn = blockIdx.x * 128;

  const f32x4 fz = {0.f, 0.f, 0.f, 0.f};
  f32x4 acc[4][4];
  #pragma unroll
  for (int i = 0; i < 4; i++)
    #pragma unroll
    for (int j = 0; j < 4; j++) acc[i][j] = fz;

  gemm_core(A, BT, lA, lB, acc, bm, bn);

  // C/D: col = lane&15, row = (lane>>4)*4 + reg
  #pragma unroll
  for (int j = 0; j < 4; j++) {
    int c = bn + wx * 64 + j * 16 + l15;
    float bvv = c < 1024 ? bq[c] : (c < 2048 ? bk[c - 1024] : bv[c - 2048]);
    int cc = c & 1023, h = cc >> 6, d = cc & 63, proj = c >> 10;
    #pragma unroll
    for (int i = 0; i < 4; i++) {
      int rbase = bm + wy * 64 + i * 16 + l4 * 4;
      #pragma unroll
      for (int r = 0; r < 4; r++) {
        float v = acc[i][j][r] + bvv;
        int row = rbase + r;
        int b = row >> 11, s = row & 2047;
        size_t qk = (((size_t)(b * NH + h)) * SS + s) * DK + d;
        if (proj == 0)
          Qh[qk] = f2bf(v * QSCALE);
        else if (proj == 1)
          Kh[qk] = f2bf(v);
        else
          VhT[(((size_t)(b * NH + h)) * DK + d) * SS + s] = f2bf(v);
      }
    }
  }
}

// Output projection: fp32 out, nt stores.
__global__ __launch_bounds__(256) void k_proj_o(const unsigned short* __restrict__ A,
                                                const unsigned short* __restrict__ BT,
                                                const float* __restrict__ bias,
                                                float* __restrict__ outp) {
  __shared__ unsigned short lA[128 * 32];
  __shared__ unsigned short lB[128 * 32];
  const int tid = threadIdx.x;
  const int lane = tid & 63, wv = tid >> 6;
  const int wy = wv >> 1, wx = wv & 1;
  const int l15 = lane & 15, l4 = lane >> 4;
  const int bm = blockIdx.y * 128, bn = blockIdx.x * 128;

  const f32x4 fz = {0.f, 0.f, 0.f, 0.f};
  f32x4 acc[4][4];
  #pragma unroll
  for (int i = 0; i < 4; i++)
    #pragma unroll
    for (int j = 0; j < 4; j++) acc[i][j] = fz;

  gemm_core(A, BT, lA, lB, acc, bm, bn);

  #pragma unroll
  for (int j = 0; j < 4; j++) {
    int c = bn + wx * 64 + j * 16 + l15;
    float bvv = bias[c];
    #pragma unroll
    for (int i = 0; i < 4; i++) {
      int rbase = bm + wy * 64 + i * 16 + l4 * 4;
      #pragma unroll
      for (int r = 0; r < 4; r++) {
        float v = acc[i][j][r] + bvv;
        __builtin_nontemporal_store(v, outp + (size_t)(rbase + r) * DM + c);
      }
    }
  }
}

// ---------------- fused attention, KVBLK=64, XCD-pinned heads ----------------
// Pass A: 6-slot K ring, 3-deep prefetch (~17us measured).
// Pass B: triple-buffered K/V + LDS-transpose P store epilogue (R9-style):
// QK writes P to swizzled LDS; after PV each wave reads back its 32x64 tile
// and stores 4x256B fully-contiguous segments per instruction (measured
// 5.0 TB/s vs ~3.5 TB/s for scattered 16-row x 64B stores).
// LDS 80KB -> 2 blocks/CU.
__global__ __launch_bounds__(256, 2) void k_attn(const unsigned short* __restrict__ Qh,
                                                 const unsigned short* __restrict__ Kh,
                                                 const unsigned short* __restrict__ VhT,
                                                 float* __restrict__ attnO,
                                                 unsigned short* __restrict__ AOh) {
  __shared__ unsigned short sm[40960];
  char* pb = (char*)(sm + 24576);  // P region (32KB): [128 rows][256B], swz ^(row&7)<<4

  const int tid = threadIdx.x;
  const int lane = tid & 63, wv = tid >> 6;
  const int l15 = lane & 15, l4 = lane >> 4;
  const int bid = blockIdx.x;
  const int xcd = bid & 7, t = bid >> 3;
  const int bh = ((t >> 4) << 3) | xcd;
  const int q0 = (t & 15) * 128;
  const size_t kbase = (size_t)bh * SS * DK;
  const f32x4 fz = {0.f, 0.f, 0.f, 0.f};

  auto stageK = [&](int kt, unsigned short* dst) {
    #pragma unroll
    for (int r = 0; r < 2; r++) {
      int chunk = r * 256 + tid;
      int row = chunk >> 3, c = chunk & 7;
      int cs = c ^ (row & 7);
      gload16(Kh + kbase + (size_t)(kt * 64 + row) * DK + cs * 8,
              (char*)dst + (r * 256 + wv * 64) * 16);
    }
  };
  auto stageV = [&](int kt, unsigned short* dst) {
    #pragma unroll
    for (int r = 0; r < 2; r++) {
      int chunk = r * 256 + tid;
      int row = chunk >> 3, c = chunk & 7;
      int cs = c ^ (row & 7);
      gload16(VhT + kbase + (size_t)row * SS + kt * 64 + cs * 8,
              (char*)dst + (r * 256 + wv * 64) * 16);
    }
  };

  s16x8 qf[2][2];
  #pragma unroll
  for (int qt = 0; qt < 2; qt++)
    #pragma unroll
    for (int ks = 0; ks < 2; ks++) {
      int row = q0 + wv * 32 + qt * 16 + l15;
      qf[qt][ks] = *(const s16x8*)&Qh[kbase + (size_t)row * DK + ks * 32 + l4 * 8];
    }

  // ---- Pass A: 6-slot ring, 3-deep prefetch ----
  float lsA[2] = {0.f, 0.f};
  stageK(0, sm);
  stageK(1, sm + 4096);
  stageK(2, sm + 8192);
  asm volatile("s_waitcnt vmcnt(4)" ::: "memory");
  __builtin_amdgcn_s_barrier();
  for (int kt = 0; kt < 32; kt++) {
    const unsigned short* kb = sm + (kt % 6) * 4096;
    if (kt < 29) stageK(kt + 3, sm + ((kt + 3) % 6) * 4096);
    #pragma unroll
    for (int nt = 0; nt < 4; nt++) {
      int krow = nt * 16 + l15;
      s16x8 kf0 = *(const s16x8*)&kb[krow * 64 + ((l4) ^ (krow & 7)) * 8];
      s16x8 kf1 = *(const s16x8*)&kb[krow * 64 + ((4 + l4) ^ (krow & 7)) * 8];
      #pragma unroll
      for (int qt = 0; qt < 2; qt++) {
        f32x4 s = fz;
        s = mfma16(kf0, qf[qt][0], s);
        s = mfma16(kf1, qf[qt][1], s);
        lsA[qt] += vexp2(s[0]) + vexp2(s[1]) + vexp2(s[2]) + vexp2(s[3]);
      }
    }
    if (kt < 29)
      asm volatile("s_waitcnt vmcnt(4)" ::: "memory");
    else if (kt == 29)
      asm volatile("s_waitcnt vmcnt(2)" ::: "memory");
    else if (kt == 30)
      asm volatile("s_waitcnt vmcnt(0)" ::: "memory");
    if (kt < 31) __builtin_amdgcn_s_barrier();
  }

  float l2l[2];
  #pragma unroll
  for (int qt = 0; qt < 2; qt++) {
    float v = lsA[qt];
    v += __shfl_xor(v, 16);
    v += __shfl_xor(v, 32);
    l2l[qt] = -vlog2(v);  // p = 2^(s + l2l)
  }

  // ---- Pass B ----
  f32x4 oacc[2][4];
  #pragma unroll
  for (int qt = 0; qt < 2; qt++)
    #pragma unroll
    for (int dt = 0; dt < 4; dt++) oacc[qt][dt] = fz;

  __builtin_amdgcn_s_barrier();  // pass-A readers done before restaging
  stageK(0, sm);
  stageV(0, sm + 12288);
  stageK(1, sm + 4096);
  stageV(1, sm + 12288 + 4096);
  asm volatile("s_waitcnt vmcnt(4)" ::: "memory");
  __builtin_amdgcn_s_barrier();

  for (int kt = 0; kt < 32; kt++) {
    int sl = kt % 3;
    const unsigned short* lk = sm + sl * 4096;
    const unsigned short* lv = sm + 12288 + sl * 4096;
    if (kt < 30) {
      int s2 = (kt + 2) % 3;
      stageK(kt + 2, sm + s2 * 4096);
      stageV(kt + 2, sm + 12288 + s2 * 4096);
    }
    // Pin issue order: this tile's 4 staging loads precede its 8 stores.
    __builtin_amdgcn_sched_barrier(0);

    // QK phase: P -> swizzled LDS (fp32) + packed bf16 in registers.
    unsigned int pw[2][4][2];
    #pragma unroll
    for (int nt = 0; nt < 4; nt++) {
      int krow = nt * 16 + l15;
      s16x8 kf0 = *(const s16x8*)&lk[krow * 64 + ((l4) ^ (krow & 7)) * 8];
      s16x8 kf1 = *(const s16x8*)&lk[krow * 64 + ((4 + l4) ^ (krow & 7)) * 8];
      #pragma unroll
      for (int qt = 0; qt < 2; qt++) {
        f32x4 s = fz;
        s = mfma16(kf0, qf[qt][0], s);
        s = mfma16(kf1, qf[qt][1], s);
        f32x4 p;
        p[0] = vexp2(s[0] + l2l[qt]);
        p[1] = vexp2(s[1] + l2l[qt]);
        p[2] = vexp2(s[2] + l2l[qt]);
        p[3] = vexp2(s[3] + l2l[qt]);
        int prow = wv * 32 + qt * 16 + l15;
        int pbyte = (prow * 256 + nt * 64 + l4 * 16) ^ ((prow & 7) << 4);
        *(f32x4*)(pb + pbyte) = p;
        pw[qt][nt][0] = cvtpk(p[0], p[1]);
        pw[qt][nt][1] = cvtpk(p[2], p[3]);
      }
    }

    // PV phase: kappa(slot 8g+4u+m) = 16u+4g+m on both P and V
    #pragma unroll
    for (int ks = 0; ks < 2; ks++) {
      s16x8 vf[4];
      #pragma unroll
      for (int dt = 0; dt < 4; dt++) {
        int vrow = dt * 16 + l15;
        int c0 = (4 * ks + (l4 >> 1)) ^ (vrow & 7);
        int c1 = (4 * ks + 2 + (l4 >> 1)) ^ (vrow & 7);
        union { unsigned long long q[2]; s16x8 v; } vv;
        vv.q[0] = *(const unsigned long long*)&lv[vrow * 64 + c0 * 8 + (l4 & 1) * 4];
        vv.q[1] = *(const unsigned long long*)&lv[vrow * 64 + c1 * 8 + (l4 & 1) * 4];
        vf[dt] = vv.v;
      }
      #pragma unroll
      for (int qt = 0; qt < 2; qt++) {
        union { unsigned int u[4]; s16x8 v; } pa;
        pa.u[0] = pw[qt][2 * ks][0];
        pa.u[1] = pw[qt][2 * ks][1];
        pa.u[2] = pw[qt][2 * ks + 1][0];
        pa.u[3] = pw[qt][2 * ks + 1][1];
        #pragma unroll
        for (int dt = 0; dt < 4; dt++)
          oacc[qt][dt] = mfma16(pa.v, vf[dt], oacc[qt][dt]);
      }
    }

    // Store epilogue: wave reads back its own 32x64 P tile and stores
    // 4 rows x 256B fully-contiguous segments per instruction.
    asm volatile("" ::: "memory");
    {
      float* gbase = attnO + ((size_t)bh * SS + q0) * SS + kt * 64 + l15 * 4;
      #pragma unroll
      for (int i = 0; i < 8; i++) {
        int rrow = wv * 32 + i * 4 + l4;
        int rbyte = (rrow * 256 + l15 * 16) ^ ((rrow & 7) << 4);
        f32x4 pv = *(const f32x4*)(pb + rbyte);
        *(f32x4*)(gbase + (size_t)rrow * SS) = pv;
      }
    }

    // Triple buffer + pinned order => vmcnt retires ONLY the previous tile's
    // 4 loads: outstanding = [kt-1: 4L+8S][kt: 4L+8S] = 24 -> vmcnt(20).
    if (kt == 0)
      asm volatile("s_waitcnt vmcnt(12)" ::: "memory");
    else if (kt < 30)
      asm volatile("s_waitcnt vmcnt(20)" ::: "memory");
    else if (kt == 30)
      asm volatile("s_waitcnt vmcnt(16)" ::: "memory");
    if (kt < 31) __builtin_amdgcn_s_barrier();
  }

  const int b = bh >> 4, h = bh & 15;
  const size_t aob = ((size_t)b * SS + q0 + wv * 32) * DM + h * DK;
  #pragma unroll
  for (int qt = 0; qt < 2; qt++)
    #pragma unroll
    for (int dt = 0; dt < 4; dt++)
      #pragma unroll
      for (int r = 0; r < 4; r++)
        AOh[aob + (size_t)(qt * 16 + l4 * 4 + r) * DM + dt * 16 + l15] =
            f2bf(oacc[qt][dt][r]);
}

extern "C" void kernel_launch(void* const* d_in, const int* in_sizes, int n_in,
                              void* d_out, int out_size, void* d_ws, size_t ws_size,
                              hipStream_t stream) {
  const float* x  = (const float*)d_in[0];
  const float* Wq = (const float*)d_in[1];
  const float* bq = (const float*)d_in[2];
  const float* Wk = (const float*)d_in[3];
  const float* bk = (const float*)d_in[4];
  const float* Wv = (const float*)d_in[5];
  const float* bv = (const float*)d_in[6];
  const float* Wo = (const float*)d_in[7];
  const float* bo = (const float*)d_in[8];

  char* ws = (char*)d_ws;
  unsigned short* xh    = (unsigned short*)(ws);
  unsigned short* WTqkv = (unsigned short*)(ws + 16777216);
  unsigned short* WTo   = (unsigned short*)(ws + 16777216 + 6291456);
  unsigned short* Qh    = (unsigned short*)(ws + 25165824);
  unsigned short* Kh    = (unsigned short*)(ws + 25165824 + 1 * 16777216);
  unsigned short* VhT   = (unsigned short*)(ws + 25165824 + 2 * 16777216);
  unsigned short* AOh   = xh;  // alias: x_bf16 dead after projections

  float* outO  = (float*)d_out;
  float* attnO = (float*)d_out + (size_t)NB * SS * DM;

  k_cvt_x<<<8192, 256, 0, stream>>>(x, xh);
  dim3 tb(32, 8), tg(32, 32, 4);
  k_cvt_w4<<<tg, tb, 0, stream>>>(Wq, Wk, Wv, Wo, WTqkv, WTo);

  dim3 pq(24, 64);
  k_proj_qkv<<<pq, 256, 0, stream>>>(xh, WTqkv, bq, bk, bv, Qh, Kh, VhT);

  k_attn<<<1024, 256, 0, stream>>>(Qh, Kh, VhT, attnO, AOh);

  dim3 po(8, 64);
  k_proj_o<<<po, 256, 0, stream>>>(AOh, WTo, bo, outO);
}

// Round 20
// 433.050 us; speedup vs baseline: 1.3249x; 1.0071x over previous
//
#include <hip/hip_runtime.h>
#include <stdint.h>

#define DM 1024
#define NH 16
#define DK 64
#define NB 4
#define SS 2048

// Q pre-scale: (1/sqrt(64)) * log2(e) so scores are in log2 domain.
#define QSCALE 0.18033688011112042f

typedef float f32x4 __attribute__((ext_vector_type(4)));
typedef short s16x8 __attribute__((ext_vector_type(8)));

typedef __attribute__((address_space(1))) unsigned int glb_u32;
typedef __attribute__((address_space(3))) unsigned int lds_u32;

static __device__ __forceinline__ void gload16(const void* g, void* lds) {
  __builtin_amdgcn_global_load_lds((glb_u32*)g, (lds_u32*)lds, 16, 0, 0);
}

static __device__ __forceinline__ unsigned short f2bf(float f) {
  union { float f; unsigned int u; } v;
  v.f = f;
  unsigned int u = v.u + 0x7fffu + ((v.u >> 16) & 1u);  // RNE
  return (unsigned short)(u >> 16);
}

static __device__ __forceinline__ unsigned int cvtpk(float lo, float hi) {
  unsigned int r;
  asm("v_cvt_pk_bf16_f32 %0, %1, %2" : "=v"(r) : "v"(lo), "v"(hi));
  return r;
}

// Bare hardware 2^x / log2(x) via compiler-known builtins.
static __device__ __forceinline__ float vexp2(float x) {
  return __builtin_amdgcn_exp2f(x);
}
static __device__ __forceinline__ float vlog2(float x) {
  return __builtin_amdgcn_logf(x);
}

static __device__ __forceinline__ f32x4 mfma16(s16x8 a, s16x8 b, f32x4 c) {
  return __builtin_amdgcn_mfma_f32_16x16x32_bf16(a, b, c, 0, 0, 0);
}

// ---------------- convert x (fp32 -> bf16), 4 elems/thread ----------------
__global__ __launch_bounds__(256) void k_cvt_x(const float* __restrict__ x,
                                               unsigned short* __restrict__ xh) {
  int i = blockIdx.x * 256 + threadIdx.x;
  float4 v = ((const float4*)x)[i];
  ushort4 h;
  h.x = f2bf(v.x); h.y = f2bf(v.y); h.z = f2bf(v.z); h.w = f2bf(v.w);
  ((ushort4*)xh)[i] = h;
}

// ------- transpose-convert 4 weights in one launch (z selects W) -------
__global__ void k_cvt_w4(const float* __restrict__ Wq, const float* __restrict__ Wk,
                         const float* __restrict__ Wv, const float* __restrict__ Wo,
                         unsigned short* __restrict__ WTqkv,
                         unsigned short* __restrict__ WTo) {
  __shared__ float t[32][33];
  int z = blockIdx.z;
  const float* W = z == 0 ? Wq : (z == 1 ? Wk : (z == 2 ? Wv : Wo));
  unsigned short* dst = z < 3 ? WTqkv + (size_t)z * 1024 * 1024 : WTo;
  int tx = threadIdx.x, ty = threadIdx.y;          // 32 x 8
  int bx = blockIdx.x * 32, by = blockIdx.y * 32;  // bx: out cols, by: in rows
  #pragma unroll
  for (int i = 0; i < 4; i++)
    t[ty + 8 * i][tx] = W[(size_t)(by + ty + 8 * i) * DM + bx + tx];
  __syncthreads();
  #pragma unroll
  for (int i = 0; i < 4; i++)
    dst[(size_t)(bx + ty + 8 * i) * DM + by + tx] = f2bf(t[tx][ty + 8 * i]);
}

// ---------------- 128x128 GEMM core (shared by both proj kernels) ----------------
static __device__ __forceinline__ void gemm_core(const unsigned short* __restrict__ A,
                                                 const unsigned short* __restrict__ BT,
                                                 unsigned short* lA, unsigned short* lB,
                                                 f32x4 acc[4][4], int bm, int bn) {
  const int tid = threadIdx.x;
  const int lane = tid & 63, wv = tid >> 6;
  const int wy = wv >> 1, wx = wv & 1;
  const int l15 = lane & 15, l4 = lane >> 4;

  for (int k0 = 0; k0 < DM; k0 += 32) {
    #pragma unroll
    for (int r = 0; r < 2; r++) {
      int chunk = r * 256 + tid;
      int row = chunk >> 2, c4 = chunk & 3;  // [128 rows][32 cols], 16B chunks
      gload16(A + (size_t)(bm + row) * DM + k0 + c4 * 8,
              (char*)lA + (r * 256 + wv * 64) * 16);
      gload16(BT + (size_t)(bn + row) * DM + k0 + c4 * 8,
              (char*)lB + (r * 256 + wv * 64) * 16);
    }
    __syncthreads();
    s16x8 af[4], bf[4];
    #pragma unroll
    for (int i = 0; i < 4; i++)
      af[i] = *(const s16x8*)&lA[(wy * 64 + i * 16 + l15) * 32 + l4 * 8];
    #pragma unroll
    for (int j = 0; j < 4; j++)
      bf[j] = *(const s16x8*)&lB[(wx * 64 + j * 16 + l15) * 32 + l4 * 8];
    #pragma unroll
    for (int i = 0; i < 4; i++)
      #pragma unroll
      for (int j = 0; j < 4; j++)
        acc[i][j] = mfma16(af[i], bf[j], acc[i][j]);
    __syncthreads();
  }
}

// Fused QKV projection: BT = stacked [3072 out][1024 in]; grid (24, 64).
__global__ __launch_bounds__(256) void k_proj_qkv(
    const unsigned short* __restrict__ A, const unsigned short* __restrict__ BT,
    const float* __restrict__ bq, const float* __restrict__ bk,
    const float* __restrict__ bv, unsigned short* __restrict__ Qh,
    unsigned short* __restrict__ Kh, unsigned short* __restrict__ VhT) {
  __shared__ unsigned short lA[128 * 32];
  __shared__ unsigned short lB[128 * 32];
  const int tid = threadIdx.x;
  const int lane = tid & 63, wv = tid >> 6;
  const int wy = wv >> 1, wx = wv & 1;
  const int l15 = lane & 15, l4 = lane >> 4;
  const int bm = blockIdx.y * 128, bn = blockIdx.x * 128;

  const f32x4 fz = {0.f, 0.f, 0.f, 0.f};
  f32x4 acc[4][4];
  #pragma unroll
  for (int i = 0; i < 4; i++)
    #pragma unroll
    for (int j = 0; j < 4; j++) acc[i][j] = fz;

  gemm_core(A, BT, lA, lB, acc, bm, bn);

  // C/D: col = lane&15, row = (lane>>4)*4 + reg
  #pragma unroll
  for (int j = 0; j < 4; j++) {
    int c = bn + wx * 64 + j * 16 + l15;
    float bvv = c < 1024 ? bq[c] : (c < 2048 ? bk[c - 1024] : bv[c - 2048]);
    int cc = c & 1023, h = cc >> 6, d = cc & 63, proj = c >> 10;
    #pragma unroll
    for (int i = 0; i < 4; i++) {
      int rbase = bm + wy * 64 + i * 16 + l4 * 4;
      #pragma unroll
      for (int r = 0; r < 4; r++) {
        float v = acc[i][j][r] + bvv;
        int row = rbase + r;
        int b = row >> 11, s = row & 2047;
        size_t qk = (((size_t)(b * NH + h)) * SS + s) * DK + d;
        if (proj == 0)
          Qh[qk] = f2bf(v * QSCALE);
        else if (proj == 1)
          Kh[qk] = f2bf(v);
        else
          VhT[(((size_t)(b * NH + h)) * DK + d) * SS + s] = f2bf(v);
      }
    }
  }
}

// Output projection: fp32 out, nt stores.
__global__ __launch_bounds__(256) void k_proj_o(const unsigned short* __restrict__ A,
                                                const unsigned short* __restrict__ BT,
                                                const float* __restrict__ bias,
                                                float* __restrict__ outp) {
  __shared__ unsigned short lA[128 * 32];
  __shared__ unsigned short lB[128 * 32];
  const int tid = threadIdx.x;
  const int lane = tid & 63, wv = tid >> 6;
  const int wy = wv >> 1, wx = wv & 1;
  const int l15 = lane & 15, l4 = lane >> 4;
  const int bm = blockIdx.y * 128, bn = blockIdx.x * 128;

  const f32x4 fz = {0.f, 0.f, 0.f, 0.f};
  f32x4 acc[4][4];
  #pragma unroll
  for (int i = 0; i < 4; i++)
    #pragma unroll
    for (int j = 0; j < 4; j++) acc[i][j] = fz;

  gemm_core(A, BT, lA, lB, acc, bm, bn);

  #pragma unroll
  for (int j = 0; j < 4; j++) {
    int c = bn + wx * 64 + j * 16 + l15;
    float bvv = bias[c];
    #pragma unroll
    for (int i = 0; i < 4; i++) {
      int rbase = bm + wy * 64 + i * 16 + l4 * 4;
      #pragma unroll
      for (int r = 0; r < 4; r++) {
        float v = acc[i][j][r] + bvv;
        __builtin_nontemporal_store(v, outp + (size_t)(rbase + r) * DM + c);
      }
    }
  }
}

// ---------------- fused attention, KVBLK=64, XCD-pinned heads ----------------
// Pass A: 6-slot K ring, 3-deep prefetch (~17us measured).
// Pass B: triple-buffered K/V + LDS-transpose P store epilogue:
// QK writes P to swizzled LDS; after PV each wave reads back its 32x64 tile
// and stores 4x256B fully-contiguous segments per instruction.
// vmcnt(20) is deliberately LOOSE (one full tile of slack): loads/stores
// retire through vmcnt out-of-order across classes, so tight counts race
// (R19 lesson). LDS 80KB -> 2 blocks/CU.
__global__ __launch_bounds__(256, 2) void k_attn(const unsigned short* __restrict__ Qh,
                                                 const unsigned short* __restrict__ Kh,
                                                 const unsigned short* __restrict__ VhT,
                                                 float* __restrict__ attnO,
                                                 unsigned short* __restrict__ AOh) {
  __shared__ unsigned short sm[40960];
  char* pb = (char*)(sm + 24576);  // P region (32KB): [128 rows][256B], swz ^(row&7)<<4

  const int tid = threadIdx.x;
  const int lane = tid & 63, wv = tid >> 6;
  const int l15 = lane & 15, l4 = lane >> 4;
  const int bid = blockIdx.x;
  const int xcd = bid & 7, t = bid >> 3;
  const int bh = ((t >> 4) << 3) | xcd;
  const int q0 = (t & 15) * 128;
  const size_t kbase = (size_t)bh * SS * DK;
  const f32x4 fz = {0.f, 0.f, 0.f, 0.f};

  auto stageK = [&](int kt, unsigned short* dst) {
    #pragma unroll
    for (int r = 0; r < 2; r++) {
      int chunk = r * 256 + tid;
      int row = chunk >> 3, c = chunk & 7;
      int cs = c ^ (row & 7);
      gload16(Kh + kbase + (size_t)(kt * 64 + row) * DK + cs * 8,
              (char*)dst + (r * 256 + wv * 64) * 16);
    }
  };
  auto stageV = [&](int kt, unsigned short* dst) {
    #pragma unroll
    for (int r = 0; r < 2; r++) {
      int chunk = r * 256 + tid;
      int row = chunk >> 3, c = chunk & 7;
      int cs = c ^ (row & 7);
      gload16(VhT + kbase + (size_t)row * SS + kt * 64 + cs * 8,
              (char*)dst + (r * 256 + wv * 64) * 16);
    }
  };

  s16x8 qf[2][2];
  #pragma unroll
  for (int qt = 0; qt < 2; qt++)
    #pragma unroll
    for (int ks = 0; ks < 2; ks++) {
      int row = q0 + wv * 32 + qt * 16 + l15;
      qf[qt][ks] = *(const s16x8*)&Qh[kbase + (size_t)row * DK + ks * 32 + l4 * 8];
    }

  // ---- Pass A: 6-slot ring, 3-deep prefetch ----
  float lsA[2] = {0.f, 0.f};
  stageK(0, sm);
  stageK(1, sm + 4096);
  stageK(2, sm + 8192);
  asm volatile("s_waitcnt vmcnt(4)" ::: "memory");
  __builtin_amdgcn_s_barrier();
  for (int kt = 0; kt < 32; kt++) {
    const unsigned short* kb = sm + (kt % 6) * 4096;
    if (kt < 29) stageK(kt + 3, sm + ((kt + 3) % 6) * 4096);
    #pragma unroll
    for (int nt = 0; nt < 4; nt++) {
      int krow = nt * 16 + l15;
      s16x8 kf0 = *(const s16x8*)&kb[krow * 64 + ((l4) ^ (krow & 7)) * 8];
      s16x8 kf1 = *(const s16x8*)&kb[krow * 64 + ((4 + l4) ^ (krow & 7)) * 8];
      #pragma unroll
      for (int qt = 0; qt < 2; qt++) {
        f32x4 s = fz;
        s = mfma16(kf0, qf[qt][0], s);
        s = mfma16(kf1, qf[qt][1], s);
        lsA[qt] += vexp2(s[0]) + vexp2(s[1]) + vexp2(s[2]) + vexp2(s[3]);
      }
    }
    if (kt < 29)
      asm volatile("s_waitcnt vmcnt(4)" ::: "memory");
    else if (kt == 29)
      asm volatile("s_waitcnt vmcnt(2)" ::: "memory");
    else if (kt == 30)
      asm volatile("s_waitcnt vmcnt(0)" ::: "memory");
    if (kt < 31) __builtin_amdgcn_s_barrier();
  }

  float l2l[2];
  #pragma unroll
  for (int qt = 0; qt < 2; qt++) {
    float v = lsA[qt];
    v += __shfl_xor(v, 16);
    v += __shfl_xor(v, 32);
    l2l[qt] = -vlog2(v);  // p = 2^(s + l2l)
  }

  // ---- Pass B ----
  f32x4 oacc[2][4];
  #pragma unroll
  for (int qt = 0; qt < 2; qt++)
    #pragma unroll
    for (int dt = 0; dt < 4; dt++) oacc[qt][dt] = fz;

  __builtin_amdgcn_s_barrier();  // pass-A readers done before restaging
  stageK(0, sm);
  stageV(0, sm + 12288);
  stageK(1, sm + 4096);
  stageV(1, sm + 12288 + 4096);
  asm volatile("s_waitcnt vmcnt(4)" ::: "memory");
  __builtin_amdgcn_s_barrier();

  for (int kt = 0; kt < 32; kt++) {
    int sl = kt % 3;
    const unsigned short* lk = sm + sl * 4096;
    const unsigned short* lv = sm + 12288 + sl * 4096;
    if (kt < 30) {
      int s2 = (kt + 2) % 3;
      stageK(kt + 2, sm + s2 * 4096);
      stageV(kt + 2, sm + 12288 + s2 * 4096);
    }
    // Pin issue order: this tile's 4 staging loads precede its 8 stores.
    __builtin_amdgcn_sched_barrier(0);

    // QK phase: P -> swizzled LDS (fp32) + packed bf16 in registers.
    unsigned int pw[2][4][2];
    #pragma unroll
    for (int nt = 0; nt < 4; nt++) {
      int krow = nt * 16 + l15;
      s16x8 kf0 = *(const s16x8*)&lk[krow * 64 + ((l4) ^ (krow & 7)) * 8];
      s16x8 kf1 = *(const s16x8*)&lk[krow * 64 + ((4 + l4) ^ (krow & 7)) * 8];
      #pragma unroll
      for (int qt = 0; qt < 2; qt++) {
        f32x4 s = fz;
        s = mfma16(kf0, qf[qt][0], s);
        s = mfma16(kf1, qf[qt][1], s);
        f32x4 p;
        p[0] = vexp2(s[0] + l2l[qt]);
        p[1] = vexp2(s[1] + l2l[qt]);
        p[2] = vexp2(s[2] + l2l[qt]);
        p[3] = vexp2(s[3] + l2l[qt]);
        int prow = wv * 32 + qt * 16 + l15;
        int pbyte = (prow * 256 + nt * 64 + l4 * 16) ^ ((prow & 7) << 4);
        *(f32x4*)(pb + pbyte) = p;
        pw[qt][nt][0] = cvtpk(p[0], p[1]);
        pw[qt][nt][1] = cvtpk(p[2], p[3]);
      }
    }

    // PV phase: kappa(slot 8g+4u+m) = 16u+4g+m on both P and V
    #pragma unroll
    for (int ks = 0; ks < 2; ks++) {
      s16x8 vf[4];
      #pragma unroll
      for (int dt = 0; dt < 4; dt++) {
        int vrow = dt * 16 + l15;
        int c0 = (4 * ks + (l4 >> 1)) ^ (vrow & 7);
        int c1 = (4 * ks + 2 + (l4 >> 1)) ^ (vrow & 7);
        union { unsigned long long q[2]; s16x8 v; } vv;
        vv.q[0] = *(const unsigned long long*)&lv[vrow * 64 + c0 * 8 + (l4 & 1) * 4];
        vv.q[1] = *(const unsigned long long*)&lv[vrow * 64 + c1 * 8 + (l4 & 1) * 4];
        vf[dt] = vv.v;
      }
      #pragma unroll
      for (int qt = 0; qt < 2; qt++) {
        union { unsigned int u[4]; s16x8 v; } pa;
        pa.u[0] = pw[qt][2 * ks][0];
        pa.u[1] = pw[qt][2 * ks][1];
        pa.u[2] = pw[qt][2 * ks + 1][0];
        pa.u[3] = pw[qt][2 * ks + 1][1];
        #pragma unroll
        for (int dt = 0; dt < 4; dt++)
          oacc[qt][dt] = mfma16(pa.v, vf[dt], oacc[qt][dt]);
      }
    }

    // Store epilogue: wave reads back its own 32x64 P tile and stores
    // 4 rows x 256B fully-contiguous segments per instruction.
    asm volatile("" ::: "memory");
    {
      float* gbase = attnO + ((size_t)bh * SS + q0) * SS + kt * 64 + l15 * 4;
      #pragma unroll
      for (int i = 0; i < 8; i++) {
        int rrow = wv * 32 + i * 4 + l4;
        int rbyte = (rrow * 256 + l15 * 16) ^ ((rrow & 7) << 4);
        f32x4 pv = *(const f32x4*)(pb + rbyte);
        *(f32x4*)(gbase + (size_t)rrow * SS) = pv;
      }
    }

    // Triple buffer + pinned order => vmcnt(20) leaves a full tile of slack
    // (loads kt+2 retired before their consumption two tiles later even with
    // cross-class OOO retirement). Stores never explicitly waited.
    if (kt == 0)
      asm volatile("s_waitcnt vmcnt(12)" ::: "memory");
    else if (kt < 30)
      asm volatile("s_waitcnt vmcnt(20)" ::: "memory");
    else if (kt == 30)
      asm volatile("s_waitcnt vmcnt(16)" ::: "memory");
    if (kt < 31) __builtin_amdgcn_s_barrier();
  }

  const int b = bh >> 4, h = bh & 15;
  const size_t aob = ((size_t)b * SS + q0 + wv * 32) * DM + h * DK;
  #pragma unroll
  for (int qt = 0; qt < 2; qt++)
    #pragma unroll
    for (int dt = 0; dt < 4; dt++)
      #pragma unroll
      for (int r = 0; r < 4; r++)
        AOh[aob + (size_t)(qt * 16 + l4 * 4 + r) * DM + dt * 16 + l15] =
            f2bf(oacc[qt][dt][r]);
}

extern "C" void kernel_launch(void* const* d_in, const int* in_sizes, int n_in,
                              void* d_out, int out_size, void* d_ws, size_t ws_size,
                              hipStream_t stream) {
  const float* x  = (const float*)d_in[0];
  const float* Wq = (const float*)d_in[1];
  const float* bq = (const float*)d_in[2];
  const float* Wk = (const float*)d_in[3];
  const float* bk = (const float*)d_in[4];
  const float* Wv = (const float*)d_in[5];
  const float* bv = (const float*)d_in[6];
  const float* Wo = (const float*)d_in[7];
  const float* bo = (const float*)d_in[8];

  char* ws = (char*)d_ws;
  unsigned short* xh    = (unsigned short*)(ws);
  unsigned short* WTqkv = (unsigned short*)(ws + 16777216);
  unsigned short* WTo   = (unsigned short*)(ws + 16777216 + 6291456);
  unsigned short* Qh    = (unsigned short*)(ws + 25165824);
  unsigned short* Kh    = (unsigned short*)(ws + 25165824 + 1 * 16777216);
  unsigned short* VhT   = (unsigned short*)(ws + 25165824 + 2 * 16777216);
  unsigned short* AOh   = xh;  // alias: x_bf16 dead after projections

  float* outO  = (float*)d_out;
  float* attnO = (float*)d_out + (size_t)NB * SS * DM;

  k_cvt_x<<<8192, 256, 0, stream>>>(x, xh);
  dim3 tb(32, 8), tg(32, 32, 4);
  k_cvt_w4<<<tg, tb, 0, stream>>>(Wq, Wk, Wv, Wo, WTqkv, WTo);

  dim3 pq(24, 64);
  k_proj_qkv<<<pq, 256, 0, stream>>>(xh, WTqkv, bq, bk, bv, Qh, Kh, VhT);

  k_attn<<<1024, 256, 0, stream>>>(Qh, Kh, VhT, attnO, AOh);

  dim3 po(8, 64);
  k_proj_o<<<po, 256, 0, stream>>>(AOh, WTo, bo, outO);
}